// Round 3
// baseline (523.037 us; speedup 1.0000x reference)
//
#include <hip/hip_runtime.h>

// Physics_Attention_Irregular_Mesh — round 5.2 (r5 + one-line compile fix:
// cast d_out to float* at the kout call site; r5.0 was infra-fail, r5.1
// failed hipcc on that cast)
// B=4, N=16384, DIM=256, H=8, D=64, G=32, inner=512. f32 I/O.
// r5 change: the projection GEMMs are fused (x read ONCE) and all big GEMMs
// drop LDS + barriers entirely — A and B fragments are read direct-global
// (B operands are tiny and L2-resident; r4 counters showed kgemm latency-
// bound: 18% HBM, 9% MFMA, 17% occupancy, 16 barriers/block).
//   kproj : fused (x@Wfx+bfx)^T -> fxT  AND  softmax(x@Wxs+bxs) -> swb,swT
//   kout  : out = swb @ ZT_b^T + bout -> d_out f32
//   k4 / k4b / k5 / kZ : unchanged (token pooling, reduce, tiny attn, fold)

typedef unsigned short u16;
typedef __attribute__((ext_vector_type(8))) unsigned short ushort8v;
typedef __attribute__((ext_vector_type(4))) unsigned short ushort4v;
typedef __attribute__((ext_vector_type(8))) short short8v;
typedef __attribute__((ext_vector_type(4))) float f32x4;

constexpr int Nc = 16384;
constexpr int BNc = 65536;

__device__ inline float b2f(u16 v) {
    union { unsigned int u; float f; } t; t.u = ((unsigned int)v) << 16; return t.f;
}
__device__ inline u16 f2b(float f) {   // round-to-nearest-even
    union { float f; unsigned int u; } t; t.f = f;
    unsigned int u = t.u;
    return (u16)((u + 0x7fffu + ((u >> 16) & 1u)) >> 16);
}

// ---------------- prep: fold WxsT[h*32+g][k] = (Wx_h @ Wslice)^T, bxs ------
__global__ __launch_bounds__(256) void k0_fold(
    const float* __restrict__ Wx, const float* __restrict__ Wslice,
    const float* __restrict__ bx, const float* __restrict__ bslice,
    u16* __restrict__ WxsT, float* __restrict__ bxs)
{
    int blk = blockIdx.x, tid = threadIdx.x;
    int h = tid >> 5, g = tid & 31;
    if (blk < 256) {
        int k = blk;
        float acc = 0.f;
        for (int d = 0; d < 64; d++)
            acc += Wx[k * 512 + h * 64 + d] * Wslice[d * 32 + g];
        WxsT[tid * 256 + k] = f2b(acc);
    } else {
        float acc = 0.f;
        for (int d = 0; d < 64; d++)
            acc += bx[h * 64 + d] * Wslice[d * 32 + g];
        bxs[tid] = acc + bslice[g];
    }
}

// ---------------- prep: WfxT[n][k] bf16 ----------------
__global__ __launch_bounds__(256) void kprep_wfx(const float* __restrict__ Wfx,
                                                 u16* __restrict__ WfxT)
{
    int n = blockIdx.x, k = threadIdx.x;        // 512 blocks x 256
    WfxT[n * 256 + k] = f2b(Wfx[k * 512 + n]);
}

// ---------------- kproj: fused projection, no LDS / no barriers ----------
// Grid 2048 x 256. Block = 32 rows of x. 4 waves: wave (wr,wc),
// wr = rows 16*wr..16*wr+15, wc = col-tile group (24 tiles of 16 cols each).
// Global tile space: nt in [0,48): nt<32 -> fx cols nt*16.., nt>=32 ->
// slice-logit cols (nt-32)*16.. . Ball = [WfxT rows 0..511 | WxsT rows 0..255].
// Frag layouts (16x16x32): A[m=lane&15][k=quad*8+j], B-row Bt[n][k] read at
// [nt*16+lm][k0+quad*8], D[row=quad*4+r][col=lane&15].
__global__ __launch_bounds__(256, 3) void kproj(
    const float* __restrict__ x, const u16* __restrict__ Ball,
    const float* __restrict__ bfx, const float* __restrict__ bxs,
    const float* __restrict__ temp,
    u16* __restrict__ fxT, u16* __restrict__ swb, u16* __restrict__ swT)
{
    int tid = threadIdx.x;
    int wave = tid >> 6, lane = tid & 63;
    int lm = lane & 15, quad = lane >> 4;
    int wr = wave & 1, wc = wave >> 1;
    int row0 = blockIdx.x * 32;
    int arow = row0 + wr * 16 + lm;

    const float* Aptr = x + (size_t)arow * 256 + quad * 8;
    const u16*   Bl   = Ball + (size_t)(wc * 384 + lm) * 256 + quad * 8;

    f32x4 acc[24] = {};

    // prefetch chunk 0 A-fragment
    f32x4 a0 = *(const f32x4*)(Aptr);
    f32x4 a1 = *(const f32x4*)(Aptr + 4);

    for (int k0 = 0; k0 < 256; k0 += 32) {
        ushort8v au;
#pragma unroll
        for (int j = 0; j < 4; j++) { au[j] = f2b(a0[j]); au[4 + j] = f2b(a1[j]); }
        short8v af = (short8v&)au;
        if (k0 < 224) {           // prefetch next chunk's A
            a0 = *(const f32x4*)(Aptr + k0 + 32);
            a1 = *(const f32x4*)(Aptr + k0 + 36);
        }
#pragma unroll
        for (int j = 0; j < 24; j++) {
            short8v bf = *(const short8v*)(Bl + (size_t)j * 4096 + k0);
            acc[j] = __builtin_amdgcn_mfma_f32_16x16x32_bf16(af, bf, acc[j], 0, 0, 0);
        }
    }

    // ---- epilogue: fx part (tiles with nt < 32) ----
    int nbase = row0 + wr * 16 + quad * 4;
    int nfx = wc ? 8 : 24;
#pragma unroll
    for (int j = 0; j < 24; j++) {
        if (j < nfx) {
            int c = (wc * 24 + j) * 16 + lm;
            float bv = bfx[c];
            ushort4v o;
#pragma unroll
            for (int r = 0; r < 4; r++) o[r] = f2b(acc[j][r] + bv);
            *(ushort4v*)(fxT + (size_t)c * 65536 + nbase) = o;
        }
    }

    // ---- epilogue: slice softmax part (wc==1 waves hold tiles 32..47) ----
    if (wc == 1) {
        int b = row0 >> 14;
        int nlbase = (row0 & 16383) + wr * 16 + quad * 4;
#pragma unroll
        for (int h = 0; h < 8; h++) {
            float it = 1.0f / temp[h];
            float bv0 = bxs[h * 32 + lm];
            float bv1 = bxs[h * 32 + 16 + lm];
            f32x4 A0 = acc[8 + 2 * h];
            f32x4 A1 = acc[9 + 2 * h];
            ushort4v p0, p1;
#pragma unroll
            for (int r = 0; r < 4; r++) {
                float v0 = (A0[r] + bv0) * it;       // g = lm
                float v1 = (A1[r] + bv1) * it;       // g = 16+lm
                float m = fmaxf(v0, v1);
                m = fmaxf(m, __shfl_xor(m, 1));
                m = fmaxf(m, __shfl_xor(m, 2));
                m = fmaxf(m, __shfl_xor(m, 4));
                m = fmaxf(m, __shfl_xor(m, 8));
                float e0 = __expf(v0 - m), e1 = __expf(v1 - m);
                float s = e0 + e1;
                s += __shfl_xor(s, 1);
                s += __shfl_xor(s, 2);
                s += __shfl_xor(s, 4);
                s += __shfl_xor(s, 8);
                float rs = 1.0f / s;
                float w0 = e0 * rs, w1 = e1 * rs;
                int row = row0 + wr * 16 + quad * 4 + r;
                swb[(size_t)row * 256 + h * 32 + lm] = f2b(w0);
                swb[(size_t)row * 256 + h * 32 + 16 + lm] = f2b(w1);
                p0[r] = f2b(w0); p1[r] = f2b(w1);
            }
            size_t gbase = (size_t)((b * 8 + h) * 32);
            *(ushort4v*)(swT + (gbase + lm) * 16384 + nlbase) = p0;
            *(ushort4v*)(swT + (gbase + 16 + lm) * 16384 + nlbase) = p1;
        }
    }
}

// ---------------- kout: out = swb @ ZT_b^T + bout, no LDS / no barriers ---
__global__ __launch_bounds__(256, 3) void kout(
    const u16* __restrict__ swb, const u16* __restrict__ ZT,
    const float* __restrict__ bout, float* __restrict__ out)
{
    int tid = threadIdx.x;
    int wave = tid >> 6, lane = tid & 63;
    int lm = lane & 15, quad = lane >> 4;
    int row0 = blockIdx.x * 64;

    const u16* Abase = swb + (size_t)(row0 + wave * 16 + lm) * 256 + quad * 8;
    const u16* Bl    = ZT + (size_t)(row0 >> 14) * 65536 + (size_t)lm * 256 + quad * 8;

    f32x4 acc[16] = {};
    short8v af = *(const short8v*)(Abase);
    for (int k0 = 0; k0 < 256; k0 += 32) {
        short8v a_cur = af;
        if (k0 < 224) af = *(const short8v*)(Abase + k0 + 32);   // prefetch
#pragma unroll
        for (int j = 0; j < 16; j++) {
            short8v bf = *(const short8v*)(Bl + (size_t)j * 4096 + k0);
            acc[j] = __builtin_amdgcn_mfma_f32_16x16x32_bf16(a_cur, bf, acc[j], 0, 0, 0);
        }
    }
#pragma unroll
    for (int j = 0; j < 16; j++) {
        int c = j * 16 + lm;
        float bv = bout[c];
#pragma unroll
        for (int r = 0; r < 4; r++)
            out[(size_t)(row0 + wave * 16 + quad * 4 + r) * 256 + c] = acc[j][r] + bv;
    }
}

// ---------------- k4: token pooling via MFMA, split-K ----------------
__global__ __launch_bounds__(256) void k4_token_mfma(
    const u16* __restrict__ swT, const u16* __restrict__ fxT,
    float* __restrict__ token_part, float* __restrict__ norm_part)
{
    int bh = blockIdx.x, ky = blockIdx.y;
    int b = bh >> 3, h = bh & 7;
    int tid = threadIdx.x, wave = tid >> 6, lane = tid & 63;
    int lm = lane & 15, quad = lane >> 4;
    int mt = wave & 1, dp = wave >> 1;
    const u16* Ar = swT + ((size_t)(bh * 32 + mt * 16 + lm)) * 16384 + ky * 512 + quad * 8;
    const u16* Br0 = fxT + ((size_t)(h * 64 + dp * 32 + lm)) * 65536
                     + (size_t)b * 16384 + ky * 512 + quad * 8;
    const u16* Br1 = Br0 + (size_t)16 * 65536;
    f32x4 acc0 = {}, acc1 = {};
    float nacc = 0.f;
#pragma unroll
    for (int kk = 0; kk < 16; kk++) {
        short8v af = *(const short8v*)(Ar + kk * 32);
        short8v b0 = *(const short8v*)(Br0 + kk * 32);
        short8v b1 = *(const short8v*)(Br1 + kk * 32);
        acc0 = __builtin_amdgcn_mfma_f32_16x16x32_bf16(af, b0, acc0, 0, 0, 0);
        acc1 = __builtin_amdgcn_mfma_f32_16x16x32_bf16(af, b1, acc1, 0, 0, 0);
        if (dp == 0) {
            ushort8v au = (ushort8v&)af;
#pragma unroll
            for (int j = 0; j < 8; j++) nacc += b2f(au[j]);
        }
    }
    float* tp = token_part + ((size_t)(ky * 32 + bh)) * 2048;
#pragma unroll
    for (int r = 0; r < 4; r++) {
        int g = mt * 16 + quad * 4 + r;
        tp[g * 64 + dp * 32 + lm] = acc0[r];
        tp[g * 64 + dp * 32 + 16 + lm] = acc1[r];
    }
    if (dp == 0) {
        nacc += __shfl_xor(nacc, 16);
        nacc += __shfl_xor(nacc, 32);
        if (lane < 16)
            norm_part[(ky * 32 + bh) * 32 + mt * 16 + lm] = nacc;
    }
}

// ---------------- k4b: reduce partials -> tl = token/(norm+1e-5) ----------
__global__ __launch_bounds__(256) void k4b_reduce(
    const float* __restrict__ tp, const float* __restrict__ np,
    float* __restrict__ tl)
{
    int t = blockIdx.x * 256 + threadIdx.x;   // 65536
    int bh = t >> 11, e = t & 2047, g = e >> 6;
    float ts = 0.f, ns = 0.f;
    for (int ch = 0; ch < 32; ch++) {
        ts += tp[((size_t)(ch * 32 + bh)) * 2048 + e];
        ns += np[(ch * 32 + bh) * 32 + g];
    }
    tl[t] = ts / (ns + 1e-5f);
}

// ---------------- k5: tiny attention over G tokens ----------------
__global__ __launch_bounds__(256) void k5_attn(
    const float* __restrict__ tlg,
    const float* __restrict__ Wq, const float* __restrict__ Wk, const float* __restrict__ Wv,
    float* __restrict__ out_slice)
{
    __shared__ float tl[32][64];
    __shared__ float ql[32][64], kl[32][64], vl[32][64];
    __shared__ float sl[32][33];
    int bh = blockIdx.x, tid = threadIdx.x;
    const float* tk = tlg + (size_t)bh * 2048;

#pragma unroll
    for (int j = 0; j < 8; j++) {
        int idx = j * 256 + tid;
        tl[idx >> 6][idx & 63] = tk[idx];
    }
    __syncthreads();
#pragma unroll
    for (int j = 0; j < 8; j++) {
        int idx = j * 256 + tid;
        int g = idx >> 6, d = idx & 63;
        float aq = 0.f, ak = 0.f, av = 0.f;
        for (int e = 0; e < 64; e++) {
            float t = tl[g][e];
            aq += t * Wq[e * 64 + d];
            ak += t * Wk[e * 64 + d];
            av += t * Wv[e * 64 + d];
        }
        ql[g][d] = aq; kl[g][d] = ak; vl[g][d] = av;
    }
    __syncthreads();
#pragma unroll
    for (int j = 0; j < 4; j++) {
        int idx = j * 256 + tid;
        int gq = idx >> 5, gk = idx & 31;
        float s = 0.f;
        for (int d = 0; d < 64; d++) s += ql[gq][d] * kl[gk][d];
        sl[gq][gk] = s * 0.125f;   // 1/sqrt(64)
    }
    __syncthreads();
    if (tid < 32) {
        float m = -1e30f;
        for (int k2 = 0; k2 < 32; k2++) m = fmaxf(m, sl[tid][k2]);
        float s = 0.f;
        for (int k2 = 0; k2 < 32; k2++) { float e = __expf(sl[tid][k2] - m); sl[tid][k2] = e; s += e; }
        float r = 1.0f / s;
        for (int k2 = 0; k2 < 32; k2++) sl[tid][k2] *= r;
    }
    __syncthreads();
#pragma unroll
    for (int j = 0; j < 8; j++) {
        int idx = j * 256 + tid;
        int g = idx >> 6, d = idx & 63;
        float a = 0.f;
        for (int k2 = 0; k2 < 32; k2++) a += sl[g][k2] * vl[k2][d];
        out_slice[(size_t)bh * 2048 + idx] = a;
    }
}

// ---------------- kZ: ZT[b][c][hg] = (os_bh @ Wout_h)^T, bf16 -------------
__global__ __launch_bounds__(256) void kZ(
    const float* __restrict__ os, const float* __restrict__ Wout,
    u16* __restrict__ ZT)
{
    int b = blockIdx.x, cb = blockIdx.y;   // grid (4, 16)
    int t = threadIdx.x;
    int c = cb * 16 + (t & 15), kq = t >> 4;
    for (int k = kq * 16; k < kq * 16 + 16; k++) {
        int h = k >> 5, g = k & 31;
        const float* osr = os + ((size_t)(b * 8 + h)) * 2048 + g * 64;
        float acc = 0.f;
        for (int d = 0; d < 64; d++)
            acc += osr[d] * Wout[(h * 64 + d) * 256 + c];
        ZT[(size_t)b * 65536 + c * 256 + k] = f2b(acc);
    }
}

// ---------------- launcher ----------------
extern "C" void kernel_launch(void* const* d_in, const int* in_sizes, int n_in,
                              void* d_out, int out_size, void* d_ws, size_t ws_size,
                              hipStream_t stream)
{
    const float* x      = (const float*)d_in[0];
    const float* Wfx    = (const float*)d_in[1];
    const float* bfx    = (const float*)d_in[2];
    const float* Wx     = (const float*)d_in[3];
    const float* bx     = (const float*)d_in[4];
    const float* Wslice = (const float*)d_in[5];
    const float* bslice = (const float*)d_in[6];
    const float* temp   = (const float*)d_in[7];
    const float* Wq     = (const float*)d_in[8];
    const float* Wk     = (const float*)d_in[9];
    const float* Wv     = (const float*)d_in[10];
    const float* Wout   = (const float*)d_in[11];
    const float* bout   = (const float*)d_in[12];

    char* ws = (char*)d_ws;
    size_t off = 0;
    auto alloc = [&](size_t bytes) {
        void* p = ws + off;
        off = (off + bytes + 255) & ~(size_t)255;
        return p;
    };
    u16*   fxT   = (u16*)  alloc((size_t)512 * BNc * 2);   // 64 MiB
    u16*   swb   = (u16*)  alloc((size_t)BNc * 256 * 2);   // 32 MiB
    u16*   swT   = (u16*)  alloc((size_t)1024 * Nc * 2);   // 32 MiB
    float* tp    = (float*)alloc((size_t)1024 * 2048 * 4); // 8 MiB
    float* np    = (float*)alloc(32768 * 4);               // 128 KiB
    float* tl    = (float*)alloc(65536 * 4);               // 256 KiB
    float* osl   = (float*)alloc(65536 * 4);               // 256 KiB
    u16*   ZT    = (u16*)  alloc(4 * 65536 * 2);           // 512 KiB
    u16*   Ball  = (u16*)  alloc((size_t)768 * 256 * 2);   // WfxT rows 0-511, WxsT rows 512-767
    float* bxs   = (float*)alloc(256 * 4);

    u16* WfxT = Ball;
    u16* WxsT = Ball + (size_t)512 * 256;

    k0_fold<<<257, 256, 0, stream>>>(Wx, Wslice, bx, bslice, WxsT, bxs);
    kprep_wfx<<<512, 256, 0, stream>>>(Wfx, WfxT);

    // fused: fxT = (x @ Wfx + bfx)^T  AND  softmax((x @ Wxs + bxs)/T) -> swb, swT
    kproj<<<2048, 256, 0, stream>>>(x, Ball, bfx, bxs, temp, fxT, swb, swT);

    k4_token_mfma<<<dim3(32, 32), 256, 0, stream>>>(swT, fxT, tp, np);
    k4b_reduce<<<256, 256, 0, stream>>>(tp, np, tl);
    k5_attn<<<32, 256, 0, stream>>>(tl, Wq, Wk, Wv, osl);
    kZ<<<dim3(4, 16), 256, 0, stream>>>(osl, Wout, ZT);

    // out = swb @ ZT_b^T + bout -> f32 d_out
    kout<<<1024, 256, 0, stream>>>(swb, ZT, bout, (float*)d_out);
}

// Round 4
// 428.264 us; speedup vs baseline: 1.2213x; 1.2213x over previous
//
#include <hip/hip_runtime.h>

// Physics_Attention_Irregular_Mesh — round 6
// B=4, N=16384, DIM=256, H=8, D=64, G=32, inner=512. f32 I/O.
// r6 change: r5's direct-global B-fragment reads were 16-way SCATTERED
// (lane stride 512B -> 16 segments per load; kproj 240us, MfmaUtil 4.3%,
// VMEM-issue bound). Fix: pre-permute B into FRAGMENT ORDER
// Bf[tile][chunk][lane][8] so each B-frag load is one coalesced 1KiB
// transaction. kZ writes ZT in fragment order directly. Structure otherwise
// unchanged: fused projection, x read once, no LDS, no barriers.
//   kfrag : repack Ball[768][256] -> Bf[48][8][64][8]   (runs once, 384KiB)
//   kproj : fused (x@Wfx+bfx)^T -> fxT AND softmax(x@Wxs+bxs) -> swb,swT
//   kout  : out = swb @ ZTf_b^T + bout -> d_out f32
//   k4 / k4b / k5 : unchanged

typedef unsigned short u16;
typedef __attribute__((ext_vector_type(8))) unsigned short ushort8v;
typedef __attribute__((ext_vector_type(4))) unsigned short ushort4v;
typedef __attribute__((ext_vector_type(8))) short short8v;
typedef __attribute__((ext_vector_type(4))) float f32x4;

constexpr int Nc = 16384;
constexpr int BNc = 65536;

__device__ inline float b2f(u16 v) {
    union { unsigned int u; float f; } t; t.u = ((unsigned int)v) << 16; return t.f;
}
__device__ inline u16 f2b(float f) {   // round-to-nearest-even
    union { float f; unsigned int u; } t; t.f = f;
    unsigned int u = t.u;
    return (u16)((u + 0x7fffu + ((u >> 16) & 1u)) >> 16);
}

// ---------------- prep: fold WxsT[h*32+g][k] = (Wx_h @ Wslice)^T, bxs ------
__global__ __launch_bounds__(256) void k0_fold(
    const float* __restrict__ Wx, const float* __restrict__ Wslice,
    const float* __restrict__ bx, const float* __restrict__ bslice,
    u16* __restrict__ WxsT, float* __restrict__ bxs)
{
    int blk = blockIdx.x, tid = threadIdx.x;
    int h = tid >> 5, g = tid & 31;
    if (blk < 256) {
        int k = blk;
        float acc = 0.f;
        for (int d = 0; d < 64; d++)
            acc += Wx[k * 512 + h * 64 + d] * Wslice[d * 32 + g];
        WxsT[tid * 256 + k] = f2b(acc);
    } else {
        float acc = 0.f;
        for (int d = 0; d < 64; d++)
            acc += bx[h * 64 + d] * Wslice[d * 32 + g];
        bxs[tid] = acc + bslice[g];
    }
}

// ---------------- prep: WfxT[n][k] bf16 ----------------
__global__ __launch_bounds__(256) void kprep_wfx(const float* __restrict__ Wfx,
                                                 u16* __restrict__ WfxT)
{
    int n = blockIdx.x, k = threadIdx.x;        // 512 blocks x 256
    WfxT[n * 256 + k] = f2b(Wfx[k * 512 + n]);
}

// ---------------- kfrag: repack Ball -> fragment-ordered Bf ----------------
// Bf[t=0..47][c=0..7][lane=0..63][jj=0..7]: lane (lm=lane&15,quad=lane>>4)
// holds Ball[t*16+lm][c*32+quad*8+jj]. A wave's frag load of (t,c) is then
// lane-contiguous: 64 lanes x 16B = one coalesced 1 KiB read.
__global__ __launch_bounds__(256) void kfrag(const u16* __restrict__ Ball,
                                             u16* __restrict__ Bf)
{
    int g = blockIdx.x * 256 + threadIdx.x;   // 96 blocks -> 24576 threads
    int pair = g >> 6, lane = g & 63;
    int t = pair >> 3, c = pair & 7;
    int n = t * 16 + (lane & 15);
    int k = c * 32 + (lane >> 4) * 8;
    ushort8v v = *(const ushort8v*)(Ball + (size_t)n * 256 + k);
    *(ushort8v*)(Bf + (size_t)(pair * 64 + lane) * 8) = v;
}

// ---------------- kproj: fused projection, no LDS / no barriers ----------
// Grid 2048 x 256. Block = 32 rows of x. 4 waves: wave (wr,wc),
// wr = rows 16*wr..+15, wc = col-tile group (24 tiles of 16 cols each).
// Global tile t = wc*24+j: t<32 -> fx cols t*16.., t>=32 -> slice logits.
// B frags from Bf (fragment-ordered, coalesced); A rows direct from x with
// register prefetch. D[row=quad*4+r][col=lane&15].
__global__ __launch_bounds__(256, 3) void kproj(
    const float* __restrict__ x, const u16* __restrict__ Bf,
    const float* __restrict__ bfx, const float* __restrict__ bxs,
    const float* __restrict__ temp,
    u16* __restrict__ fxT, u16* __restrict__ swb, u16* __restrict__ swT)
{
    int tid = threadIdx.x;
    int wave = tid >> 6, lane = tid & 63;
    int lm = lane & 15, quad = lane >> 4;
    int wr = wave & 1, wc = wave >> 1;
    int row0 = blockIdx.x * 32;
    int arow = row0 + wr * 16 + lm;

    const float* Aptr = x + (size_t)arow * 256 + quad * 8;
    const u16*   Bl   = Bf + (size_t)(wc * 192) * 512 + (size_t)lane * 8;

    f32x4 acc[24] = {};

    // prefetch chunk 0 A-fragment
    f32x4 a0 = *(const f32x4*)(Aptr);
    f32x4 a1 = *(const f32x4*)(Aptr + 4);

    for (int k0 = 0; k0 < 256; k0 += 32) {
        ushort8v au;
#pragma unroll
        for (int j = 0; j < 4; j++) { au[j] = f2b(a0[j]); au[4 + j] = f2b(a1[j]); }
        short8v af = (short8v&)au;
        if (k0 < 224) {           // prefetch next chunk's A
            a0 = *(const f32x4*)(Aptr + k0 + 32);
            a1 = *(const f32x4*)(Aptr + k0 + 36);
        }
        const u16* Bc = Bl + (size_t)(k0 >> 5) * 512;
#pragma unroll
        for (int j = 0; j < 24; j++) {
            short8v bf = *(const short8v*)(Bc + (size_t)j * 4096);
            acc[j] = __builtin_amdgcn_mfma_f32_16x16x32_bf16(af, bf, acc[j], 0, 0, 0);
        }
    }

    // ---- epilogue: fx part (tiles with t < 32) ----
    int nbase = row0 + wr * 16 + quad * 4;
    int nfx = wc ? 8 : 24;
#pragma unroll
    for (int j = 0; j < 24; j++) {
        if (j < nfx) {
            int c = (wc * 24 + j) * 16 + lm;
            float bv = bfx[c];
            ushort4v o;
#pragma unroll
            for (int r = 0; r < 4; r++) o[r] = f2b(acc[j][r] + bv);
            *(ushort4v*)(fxT + (size_t)c * 65536 + nbase) = o;
        }
    }

    // ---- epilogue: slice softmax part (wc==1 waves hold tiles 32..47) ----
    if (wc == 1) {
        int b = row0 >> 14;
        int nlbase = (row0 & 16383) + wr * 16 + quad * 4;
#pragma unroll
        for (int h = 0; h < 8; h++) {
            float it = 1.0f / temp[h];
            float bv0 = bxs[h * 32 + lm];
            float bv1 = bxs[h * 32 + 16 + lm];
            f32x4 A0 = acc[8 + 2 * h];
            f32x4 A1 = acc[9 + 2 * h];
            ushort4v p0, p1;
#pragma unroll
            for (int r = 0; r < 4; r++) {
                float v0 = (A0[r] + bv0) * it;       // g = lm
                float v1 = (A1[r] + bv1) * it;       // g = 16+lm
                float m = fmaxf(v0, v1);
                m = fmaxf(m, __shfl_xor(m, 1));
                m = fmaxf(m, __shfl_xor(m, 2));
                m = fmaxf(m, __shfl_xor(m, 4));
                m = fmaxf(m, __shfl_xor(m, 8));
                float e0 = __expf(v0 - m), e1 = __expf(v1 - m);
                float s = e0 + e1;
                s += __shfl_xor(s, 1);
                s += __shfl_xor(s, 2);
                s += __shfl_xor(s, 4);
                s += __shfl_xor(s, 8);
                float rs = 1.0f / s;
                float w0 = e0 * rs, w1 = e1 * rs;
                int row = row0 + wr * 16 + quad * 4 + r;
                swb[(size_t)row * 256 + h * 32 + lm] = f2b(w0);
                swb[(size_t)row * 256 + h * 32 + 16 + lm] = f2b(w1);
                p0[r] = f2b(w0); p1[r] = f2b(w1);
            }
            size_t gbase = (size_t)((b * 8 + h) * 32);
            *(ushort4v*)(swT + (gbase + lm) * 16384 + nlbase) = p0;
            *(ushort4v*)(swT + (gbase + 16 + lm) * 16384 + nlbase) = p1;
        }
    }
}

// ---------------- kout: out = swb @ ZTf_b^T + bout, frag-ordered B --------
__global__ __launch_bounds__(256, 3) void kout(
    const u16* __restrict__ swb, const u16* __restrict__ ZTf,
    const float* __restrict__ bout, float* __restrict__ out)
{
    int tid = threadIdx.x;
    int wave = tid >> 6, lane = tid & 63;
    int lm = lane & 15, quad = lane >> 4;
    int row0 = blockIdx.x * 64;

    const u16* Abase = swb + (size_t)(row0 + wave * 16 + lm) * 256 + quad * 8;
    const u16* Bl    = ZTf + (size_t)(row0 >> 14) * 65536 + (size_t)lane * 8;

    f32x4 acc[16] = {};
    short8v af = *(const short8v*)(Abase);
    for (int k0 = 0; k0 < 256; k0 += 32) {
        short8v a_cur = af;
        if (k0 < 224) af = *(const short8v*)(Abase + k0 + 32);   // prefetch
        const u16* Bc = Bl + (size_t)(k0 >> 5) * 512;
#pragma unroll
        for (int j = 0; j < 16; j++) {
            short8v bf = *(const short8v*)(Bc + (size_t)j * 4096);
            acc[j] = __builtin_amdgcn_mfma_f32_16x16x32_bf16(a_cur, bf, acc[j], 0, 0, 0);
        }
    }
#pragma unroll
    for (int j = 0; j < 16; j++) {
        int c = j * 16 + lm;
        float bv = bout[c];
#pragma unroll
        for (int r = 0; r < 4; r++)
            out[(size_t)(row0 + wave * 16 + quad * 4 + r) * 256 + c] = acc[j][r] + bv;
    }
}

// ---------------- k4: token pooling via MFMA, split-K ----------------
__global__ __launch_bounds__(256) void k4_token_mfma(
    const u16* __restrict__ swT, const u16* __restrict__ fxT,
    float* __restrict__ token_part, float* __restrict__ norm_part)
{
    int bh = blockIdx.x, ky = blockIdx.y;
    int b = bh >> 3, h = bh & 7;
    int tid = threadIdx.x, wave = tid >> 6, lane = tid & 63;
    int lm = lane & 15, quad = lane >> 4;
    int mt = wave & 1, dp = wave >> 1;
    const u16* Ar = swT + ((size_t)(bh * 32 + mt * 16 + lm)) * 16384 + ky * 512 + quad * 8;
    const u16* Br0 = fxT + ((size_t)(h * 64 + dp * 32 + lm)) * 65536
                     + (size_t)b * 16384 + ky * 512 + quad * 8;
    const u16* Br1 = Br0 + (size_t)16 * 65536;
    f32x4 acc0 = {}, acc1 = {};
    float nacc = 0.f;
#pragma unroll
    for (int kk = 0; kk < 16; kk++) {
        short8v af = *(const short8v*)(Ar + kk * 32);
        short8v b0 = *(const short8v*)(Br0 + kk * 32);
        short8v b1 = *(const short8v*)(Br1 + kk * 32);
        acc0 = __builtin_amdgcn_mfma_f32_16x16x32_bf16(af, b0, acc0, 0, 0, 0);
        acc1 = __builtin_amdgcn_mfma_f32_16x16x32_bf16(af, b1, acc1, 0, 0, 0);
        if (dp == 0) {
            ushort8v au = (ushort8v&)af;
#pragma unroll
            for (int j = 0; j < 8; j++) nacc += b2f(au[j]);
        }
    }
    float* tp = token_part + ((size_t)(ky * 32 + bh)) * 2048;
#pragma unroll
    for (int r = 0; r < 4; r++) {
        int g = mt * 16 + quad * 4 + r;
        tp[g * 64 + dp * 32 + lm] = acc0[r];
        tp[g * 64 + dp * 32 + 16 + lm] = acc1[r];
    }
    if (dp == 0) {
        nacc += __shfl_xor(nacc, 16);
        nacc += __shfl_xor(nacc, 32);
        if (lane < 16)
            norm_part[(ky * 32 + bh) * 32 + mt * 16 + lm] = nacc;
    }
}

// ---------------- k4b: reduce partials -> tl = token/(norm+1e-5) ----------
__global__ __launch_bounds__(256) void k4b_reduce(
    const float* __restrict__ tp, const float* __restrict__ np,
    float* __restrict__ tl)
{
    int t = blockIdx.x * 256 + threadIdx.x;   // 65536
    int bh = t >> 11, e = t & 2047, g = e >> 6;
    float ts = 0.f, ns = 0.f;
    for (int ch = 0; ch < 32; ch++) {
        ts += tp[((size_t)(ch * 32 + bh)) * 2048 + e];
        ns += np[(ch * 32 + bh) * 32 + g];
    }
    tl[t] = ts / (ns + 1e-5f);
}

// ---------------- k5: tiny attention over G tokens ----------------
__global__ __launch_bounds__(256) void k5_attn(
    const float* __restrict__ tlg,
    const float* __restrict__ Wq, const float* __restrict__ Wk, const float* __restrict__ Wv,
    float* __restrict__ out_slice)
{
    __shared__ float tl[32][64];
    __shared__ float ql[32][64], kl[32][64], vl[32][64];
    __shared__ float sl[32][33];
    int bh = blockIdx.x, tid = threadIdx.x;
    const float* tk = tlg + (size_t)bh * 2048;

#pragma unroll
    for (int j = 0; j < 8; j++) {
        int idx = j * 256 + tid;
        tl[idx >> 6][idx & 63] = tk[idx];
    }
    __syncthreads();
#pragma unroll
    for (int j = 0; j < 8; j++) {
        int idx = j * 256 + tid;
        int g = idx >> 6, d = idx & 63;
        float aq = 0.f, ak = 0.f, av = 0.f;
        for (int e = 0; e < 64; e++) {
            float t = tl[g][e];
            aq += t * Wq[e * 64 + d];
            ak += t * Wk[e * 64 + d];
            av += t * Wv[e * 64 + d];
        }
        ql[g][d] = aq; kl[g][d] = ak; vl[g][d] = av;
    }
    __syncthreads();
#pragma unroll
    for (int j = 0; j < 4; j++) {
        int idx = j * 256 + tid;
        int gq = idx >> 5, gk = idx & 31;
        float s = 0.f;
        for (int d = 0; d < 64; d++) s += ql[gq][d] * kl[gk][d];
        sl[gq][gk] = s * 0.125f;   // 1/sqrt(64)
    }
    __syncthreads();
    if (tid < 32) {
        float m = -1e30f;
        for (int k2 = 0; k2 < 32; k2++) m = fmaxf(m, sl[tid][k2]);
        float s = 0.f;
        for (int k2 = 0; k2 < 32; k2++) { float e = __expf(sl[tid][k2] - m); sl[tid][k2] = e; s += e; }
        float r = 1.0f / s;
        for (int k2 = 0; k2 < 32; k2++) sl[tid][k2] *= r;
    }
    __syncthreads();
#pragma unroll
    for (int j = 0; j < 8; j++) {
        int idx = j * 256 + tid;
        int g = idx >> 6, d = idx & 63;
        float a = 0.f;
        for (int k2 = 0; k2 < 32; k2++) a += sl[g][k2] * vl[k2][d];
        out_slice[(size_t)bh * 2048 + idx] = a;
    }
}

// ---------------- kZ: ZTf[b][t][c][lane][8] = frag-ordered (os@Wout)^T ----
__global__ __launch_bounds__(256) void kZ(
    const float* __restrict__ os, const float* __restrict__ Wout,
    u16* __restrict__ ZTf)
{
    int b = blockIdx.x, cb = blockIdx.y;   // grid (4, 16)
    int t = threadIdx.x;
    int c = cb * 16 + (t & 15), kq = t >> 4;
    int tile = c >> 4, lm = c & 15;
    for (int k = kq * 16; k < kq * 16 + 16; k++) {
        int h = k >> 5, g = k & 31;
        const float* osr = os + ((size_t)(b * 8 + h)) * 2048 + g * 64;
        float acc = 0.f;
        for (int d = 0; d < 64; d++)
            acc += osr[d] * Wout[(h * 64 + d) * 256 + c];
        int ch = k >> 5, quad = (k >> 3) & 3, jj = k & 7;
        int lane = quad * 16 + lm;
        ZTf[((size_t)((b * 16 + tile) * 8 + ch)) * 512 + lane * 8 + jj] = f2b(acc);
    }
}

// ---------------- launcher ----------------
extern "C" void kernel_launch(void* const* d_in, const int* in_sizes, int n_in,
                              void* d_out, int out_size, void* d_ws, size_t ws_size,
                              hipStream_t stream)
{
    const float* x      = (const float*)d_in[0];
    const float* Wfx    = (const float*)d_in[1];
    const float* bfx    = (const float*)d_in[2];
    const float* Wx     = (const float*)d_in[3];
    const float* bx     = (const float*)d_in[4];
    const float* Wslice = (const float*)d_in[5];
    const float* bslice = (const float*)d_in[6];
    const float* temp   = (const float*)d_in[7];
    const float* Wq     = (const float*)d_in[8];
    const float* Wk     = (const float*)d_in[9];
    const float* Wv     = (const float*)d_in[10];
    const float* Wout   = (const float*)d_in[11];
    const float* bout   = (const float*)d_in[12];

    char* ws = (char*)d_ws;
    size_t off = 0;
    auto alloc = [&](size_t bytes) {
        void* p = ws + off;
        off = (off + bytes + 255) & ~(size_t)255;
        return p;
    };
    u16*   fxT   = (u16*)  alloc((size_t)512 * BNc * 2);   // 64 MiB
    u16*   swb   = (u16*)  alloc((size_t)BNc * 256 * 2);   // 32 MiB
    u16*   swT   = (u16*)  alloc((size_t)1024 * Nc * 2);   // 32 MiB
    float* tp    = (float*)alloc((size_t)1024 * 2048 * 4); // 8 MiB
    float* np    = (float*)alloc(32768 * 4);               // 128 KiB
    float* tl    = (float*)alloc(65536 * 4);               // 256 KiB
    float* osl   = (float*)alloc(65536 * 4);               // 256 KiB
    u16*   ZTf   = (u16*)  alloc(4 * 65536 * 2);           // 512 KiB, frag-ordered
    u16*   Ball  = (u16*)  alloc((size_t)768 * 256 * 2);   // WfxT rows 0-511, WxsT 512-767
    u16*   Bfrg  = (u16*)  alloc((size_t)768 * 256 * 2);   // fragment-ordered Ball
    float* bxs   = (float*)alloc(256 * 4);

    u16* WfxT = Ball;
    u16* WxsT = Ball + (size_t)512 * 256;

    k0_fold<<<257, 256, 0, stream>>>(Wx, Wslice, bx, bslice, WxsT, bxs);
    kprep_wfx<<<512, 256, 0, stream>>>(Wfx, WfxT);
    kfrag<<<96, 256, 0, stream>>>(Ball, Bfrg);

    // fused: fxT = (x @ Wfx + bfx)^T  AND  softmax((x @ Wxs + bxs)/T) -> swb, swT
    kproj<<<2048, 256, 0, stream>>>(x, Bfrg, bfx, bxs, temp, fxT, swb, swT);

    k4_token_mfma<<<dim3(32, 32), 256, 0, stream>>>(swT, fxT, tp, np);
    k4b_reduce<<<256, 256, 0, stream>>>(tp, np, tl);
    k5_attn<<<32, 256, 0, stream>>>(tl, Wq, Wk, Wv, osl);
    kZ<<<dim3(4, 16), 256, 0, stream>>>(osl, Wout, ZTf);

    // out = swb @ ZTf_b^T + bout -> f32 d_out
    kout<<<1024, 256, 0, stream>>>(swb, ZTf, bout, (float*)d_out);
}

// Round 5
// 391.403 us; speedup vs baseline: 1.3363x; 1.0942x over previous
//
#include <hip/hip_runtime.h>

// Physics_Attention_Irregular_Mesh — round 7
// B=4, N=16384, DIM=256, H=8, D=64, G=32, inner=512. f32 I/O.
// r7: r6's direct-global B was L1-BW/latency bound (6 MiB L1 traffic per CU,
// 24 B-frags can't stay in flight in 64 VGPR -> MfmaUtil 6.5%). Restore LDS
// staging for B (r4's proven structure) while KEEPING r5's fusion (x read
// once) and r6's fragment-order repack (now chunk-major so each per-chunk
// stage is one contiguous 48 KiB; coalesced loads, conflict-free b128 LDS).
// A stays direct-global with register prefetch.
//   kfrag : repack Ball[768][256] -> Bf[chunk][tile][lane][8]
//   kproj : fused (x@Wfx+bfx)^T -> fxT AND softmax(x@Wxs+bxs) -> swb,swT
//   kout  : out = swb @ ZTf_b^T + bout (ZTf chunk-major from kZ)
//   k4 / k4b / k5 : unchanged

typedef unsigned short u16;
typedef __attribute__((ext_vector_type(8))) unsigned short ushort8v;
typedef __attribute__((ext_vector_type(4))) unsigned short ushort4v;
typedef __attribute__((ext_vector_type(8))) short short8v;
typedef __attribute__((ext_vector_type(4))) float f32x4;

constexpr int Nc = 16384;
constexpr int BNc = 65536;

__device__ inline float b2f(u16 v) {
    union { unsigned int u; float f; } t; t.u = ((unsigned int)v) << 16; return t.f;
}
__device__ inline u16 f2b(float f) {   // round-to-nearest-even
    union { float f; unsigned int u; } t; t.f = f;
    unsigned int u = t.u;
    return (u16)((u + 0x7fffu + ((u >> 16) & 1u)) >> 16);
}

// ---------------- prep: fold WxsT[h*32+g][k] = (Wx_h @ Wslice)^T, bxs ------
__global__ __launch_bounds__(256) void k0_fold(
    const float* __restrict__ Wx, const float* __restrict__ Wslice,
    const float* __restrict__ bx, const float* __restrict__ bslice,
    u16* __restrict__ WxsT, float* __restrict__ bxs)
{
    int blk = blockIdx.x, tid = threadIdx.x;
    int h = tid >> 5, g = tid & 31;
    if (blk < 256) {
        int k = blk;
        float acc = 0.f;
        for (int d = 0; d < 64; d++)
            acc += Wx[k * 512 + h * 64 + d] * Wslice[d * 32 + g];
        WxsT[tid * 256 + k] = f2b(acc);
    } else {
        float acc = 0.f;
        for (int d = 0; d < 64; d++)
            acc += bx[h * 64 + d] * Wslice[d * 32 + g];
        bxs[tid] = acc + bslice[g];
    }
}

// ---------------- prep: WfxT[n][k] bf16 ----------------
__global__ __launch_bounds__(256) void kprep_wfx(const float* __restrict__ Wfx,
                                                 u16* __restrict__ WfxT)
{
    int n = blockIdx.x, k = threadIdx.x;        // 512 blocks x 256
    WfxT[n * 256 + k] = f2b(Wfx[k * 512 + n]);
}

// ---------------- kfrag: repack Ball -> chunk-major fragment order --------
// Bf[c=0..7][t=0..47][lane=0..63][jj=0..7]: lane (lm,quad) holds
// Ball[t*16+lm][c*32+quad*8+jj]. One chunk c = contiguous 48 KiB.
__global__ __launch_bounds__(256) void kfrag(const u16* __restrict__ Ball,
                                             u16* __restrict__ Bf)
{
    int g = blockIdx.x * 256 + threadIdx.x;   // 96 blocks -> 24576 threads
    int pair = g >> 6, lane = g & 63;
    int t = pair >> 3, c = pair & 7;
    int n = t * 16 + (lane & 15);
    int k = c * 32 + (lane >> 4) * 8;
    ushort8v v = *(const ushort8v*)(Ball + (size_t)n * 256 + k);
    *(ushort8v*)(Bf + (size_t)((c * 48 + t) * 64 + lane) * 8) = v;
}

// ---------------- kproj: fused projection, LDS-staged B -------------------
// Grid 2048 x 256. Block = 32 rows x 48 tiles (full fused width). 4 waves:
// wr = wave&1 (16-row group), wc = wave>>1 (24-tile group). Per k-chunk of
// 32: each wave stages 12 tiles (12 coalesced 16B/lane loads -> ds_write
// b128), barrier, 24 ds_read_b128 + 24 MFMA, barrier. A direct-global with
// register prefetch. D[row=quad*4+r][col=lane&15].
__global__ __launch_bounds__(256, 3) void kproj(
    const float* __restrict__ x, const u16* __restrict__ Bf,
    const float* __restrict__ bfx, const float* __restrict__ bxs,
    const float* __restrict__ temp,
    u16* __restrict__ fxT, u16* __restrict__ swb, u16* __restrict__ swT)
{
    __shared__ u16 Bs[48 * 512];    // 48 KiB: [tile][lane][8]
    int tid = threadIdx.x;
    int wave = tid >> 6, lane = tid & 63;
    int lm = lane & 15, quad = lane >> 4;
    int wr = wave & 1, wc = wave >> 1;
    int row0 = blockIdx.x * 32;
    int arow = row0 + wr * 16 + lm;

    const float* Aptr = x + (size_t)arow * 256 + quad * 8;

    f32x4 acc[24] = {};

    // prefetch chunk 0 A-fragment
    f32x4 a0 = *(const f32x4*)(Aptr);
    f32x4 a1 = *(const f32x4*)(Aptr + 4);

    for (int c = 0; c < 8; c++) {
        // stage B chunk c: this wave stages tiles [wave*12, wave*12+12)
        const u16* src = Bf + (size_t)c * 24576 + (size_t)(wave * 12) * 512 + lane * 8;
#pragma unroll
        for (int i = 0; i < 12; i++) {
            ushort8v v = *(const ushort8v*)(src + i * 512);
            *(ushort8v*)&Bs[(wave * 12 + i) * 512 + lane * 8] = v;
        }
        ushort8v au;
#pragma unroll
        for (int j = 0; j < 4; j++) { au[j] = f2b(a0[j]); au[4 + j] = f2b(a1[j]); }
        short8v af = (short8v&)au;
        if (c < 7) {              // prefetch next chunk's A
            a0 = *(const f32x4*)(Aptr + c * 32 + 32);
            a1 = *(const f32x4*)(Aptr + c * 32 + 36);
        }
        __syncthreads();
#pragma unroll
        for (int j = 0; j < 24; j++) {
            short8v bf = *(short8v*)&Bs[(wc * 24 + j) * 512 + lane * 8];
            acc[j] = __builtin_amdgcn_mfma_f32_16x16x32_bf16(af, bf, acc[j], 0, 0, 0);
        }
        __syncthreads();
    }

    // ---- epilogue: fx part (tiles with t < 32) ----
    int nbase = row0 + wr * 16 + quad * 4;
    int nfx = wc ? 8 : 24;
#pragma unroll
    for (int j = 0; j < 24; j++) {
        if (j < nfx) {
            int cc = (wc * 24 + j) * 16 + lm;
            float bv = bfx[cc];
            ushort4v o;
#pragma unroll
            for (int r = 0; r < 4; r++) o[r] = f2b(acc[j][r] + bv);
            *(ushort4v*)(fxT + (size_t)cc * 65536 + nbase) = o;
        }
    }

    // ---- epilogue: slice softmax part (wc==1 waves hold tiles 32..47) ----
    if (wc == 1) {
        int b = row0 >> 14;
        int nlbase = (row0 & 16383) + wr * 16 + quad * 4;
#pragma unroll
        for (int h = 0; h < 8; h++) {
            float it = 1.0f / temp[h];
            float bv0 = bxs[h * 32 + lm];
            float bv1 = bxs[h * 32 + 16 + lm];
            f32x4 A0 = acc[8 + 2 * h];
            f32x4 A1 = acc[9 + 2 * h];
            ushort4v p0, p1;
#pragma unroll
            for (int r = 0; r < 4; r++) {
                float v0 = (A0[r] + bv0) * it;       // g = lm
                float v1 = (A1[r] + bv1) * it;       // g = 16+lm
                float m = fmaxf(v0, v1);
                m = fmaxf(m, __shfl_xor(m, 1));
                m = fmaxf(m, __shfl_xor(m, 2));
                m = fmaxf(m, __shfl_xor(m, 4));
                m = fmaxf(m, __shfl_xor(m, 8));
                float e0 = __expf(v0 - m), e1 = __expf(v1 - m);
                float s = e0 + e1;
                s += __shfl_xor(s, 1);
                s += __shfl_xor(s, 2);
                s += __shfl_xor(s, 4);
                s += __shfl_xor(s, 8);
                float rs = 1.0f / s;
                float w0 = e0 * rs, w1 = e1 * rs;
                int row = row0 + wr * 16 + quad * 4 + r;
                swb[(size_t)row * 256 + h * 32 + lm] = f2b(w0);
                swb[(size_t)row * 256 + h * 32 + 16 + lm] = f2b(w1);
                p0[r] = f2b(w0); p1[r] = f2b(w1);
            }
            size_t gbase = (size_t)((b * 8 + h) * 32);
            *(ushort4v*)(swT + (gbase + lm) * 16384 + nlbase) = p0;
            *(ushort4v*)(swT + (gbase + 16 + lm) * 16384 + nlbase) = p1;
        }
    }
}

// ---------------- kout: out = swb @ ZTf_b^T + bout, LDS-staged B ----------
// ZTf is chunk-major: [b][c=0..7][tile=0..15][lane][8]. Per chunk stage
// 16 KiB (4 tiles per wave), barrier, 16 ds_read+MFMA, barrier.
__global__ __launch_bounds__(256, 4) void kout(
    const u16* __restrict__ swb, const u16* __restrict__ ZTf,
    const float* __restrict__ bout, float* __restrict__ out)
{
    __shared__ u16 Bs[16 * 512];    // 16 KiB
    int tid = threadIdx.x;
    int wave = tid >> 6, lane = tid & 63;
    int lm = lane & 15, quad = lane >> 4;
    int row0 = blockIdx.x * 64;

    const u16* Abase = swb + (size_t)(row0 + wave * 16 + lm) * 256 + quad * 8;
    const u16* Zb    = ZTf + (size_t)(row0 >> 14) * 65536;

    f32x4 acc[16] = {};
    short8v af = *(const short8v*)(Abase);
    for (int c = 0; c < 8; c++) {
        const u16* src = Zb + (size_t)c * 8192 + (size_t)(wave * 4) * 512 + lane * 8;
#pragma unroll
        for (int i = 0; i < 4; i++) {
            ushort8v v = *(const ushort8v*)(src + i * 512);
            *(ushort8v*)&Bs[(wave * 4 + i) * 512 + lane * 8] = v;
        }
        short8v a_cur = af;
        if (c < 7) af = *(const short8v*)(Abase + c * 32 + 32);   // prefetch
        __syncthreads();
#pragma unroll
        for (int j = 0; j < 16; j++) {
            short8v bf = *(short8v*)&Bs[j * 512 + lane * 8];
            acc[j] = __builtin_amdgcn_mfma_f32_16x16x32_bf16(a_cur, bf, acc[j], 0, 0, 0);
        }
        __syncthreads();
    }
#pragma unroll
    for (int j = 0; j < 16; j++) {
        int cc = j * 16 + lm;
        float bv = bout[cc];
#pragma unroll
        for (int r = 0; r < 4; r++)
            out[(size_t)(row0 + wave * 16 + quad * 4 + r) * 256 + cc] = acc[j][r] + bv;
    }
}

// ---------------- k4: token pooling via MFMA, split-K ----------------
__global__ __launch_bounds__(256) void k4_token_mfma(
    const u16* __restrict__ swT, const u16* __restrict__ fxT,
    float* __restrict__ token_part, float* __restrict__ norm_part)
{
    int bh = blockIdx.x, ky = blockIdx.y;
    int b = bh >> 3, h = bh & 7;
    int tid = threadIdx.x, wave = tid >> 6, lane = tid & 63;
    int lm = lane & 15, quad = lane >> 4;
    int mt = wave & 1, dp = wave >> 1;
    const u16* Ar = swT + ((size_t)(bh * 32 + mt * 16 + lm)) * 16384 + ky * 512 + quad * 8;
    const u16* Br0 = fxT + ((size_t)(h * 64 + dp * 32 + lm)) * 65536
                     + (size_t)b * 16384 + ky * 512 + quad * 8;
    const u16* Br1 = Br0 + (size_t)16 * 65536;
    f32x4 acc0 = {}, acc1 = {};
    float nacc = 0.f;
#pragma unroll
    for (int kk = 0; kk < 16; kk++) {
        short8v af = *(const short8v*)(Ar + kk * 32);
        short8v b0 = *(const short8v*)(Br0 + kk * 32);
        short8v b1 = *(const short8v*)(Br1 + kk * 32);
        acc0 = __builtin_amdgcn_mfma_f32_16x16x32_bf16(af, b0, acc0, 0, 0, 0);
        acc1 = __builtin_amdgcn_mfma_f32_16x16x32_bf16(af, b1, acc1, 0, 0, 0);
        if (dp == 0) {
            ushort8v au = (ushort8v&)af;
#pragma unroll
            for (int j = 0; j < 8; j++) nacc += b2f(au[j]);
        }
    }
    float* tp = token_part + ((size_t)(ky * 32 + bh)) * 2048;
#pragma unroll
    for (int r = 0; r < 4; r++) {
        int g = mt * 16 + quad * 4 + r;
        tp[g * 64 + dp * 32 + lm] = acc0[r];
        tp[g * 64 + dp * 32 + 16 + lm] = acc1[r];
    }
    if (dp == 0) {
        nacc += __shfl_xor(nacc, 16);
        nacc += __shfl_xor(nacc, 32);
        if (lane < 16)
            norm_part[(ky * 32 + bh) * 32 + mt * 16 + lm] = nacc;
    }
}

// ---------------- k4b: reduce partials -> tl = token/(norm+1e-5) ----------
__global__ __launch_bounds__(256) void k4b_reduce(
    const float* __restrict__ tp, const float* __restrict__ np,
    float* __restrict__ tl)
{
    int t = blockIdx.x * 256 + threadIdx.x;   // 65536
    int bh = t >> 11, e = t & 2047, g = e >> 6;
    float ts = 0.f, ns = 0.f;
    for (int ch = 0; ch < 32; ch++) {
        ts += tp[((size_t)(ch * 32 + bh)) * 2048 + e];
        ns += np[(ch * 32 + bh) * 32 + g];
    }
    tl[t] = ts / (ns + 1e-5f);
}

// ---------------- k5: tiny attention over G tokens ----------------
__global__ __launch_bounds__(256) void k5_attn(
    const float* __restrict__ tlg,
    const float* __restrict__ Wq, const float* __restrict__ Wk, const float* __restrict__ Wv,
    float* __restrict__ out_slice)
{
    __shared__ float tl[32][64];
    __shared__ float ql[32][64], kl[32][64], vl[32][64];
    __shared__ float sl[32][33];
    int bh = blockIdx.x, tid = threadIdx.x;
    const float* tk = tlg + (size_t)bh * 2048;

#pragma unroll
    for (int j = 0; j < 8; j++) {
        int idx = j * 256 + tid;
        tl[idx >> 6][idx & 63] = tk[idx];
    }
    __syncthreads();
#pragma unroll
    for (int j = 0; j < 8; j++) {
        int idx = j * 256 + tid;
        int g = idx >> 6, d = idx & 63;
        float aq = 0.f, ak = 0.f, av = 0.f;
        for (int e = 0; e < 64; e++) {
            float t = tl[g][e];
            aq += t * Wq[e * 64 + d];
            ak += t * Wk[e * 64 + d];
            av += t * Wv[e * 64 + d];
        }
        ql[g][d] = aq; kl[g][d] = ak; vl[g][d] = av;
    }
    __syncthreads();
#pragma unroll
    for (int j = 0; j < 4; j++) {
        int idx = j * 256 + tid;
        int gq = idx >> 5, gk = idx & 31;
        float s = 0.f;
        for (int d = 0; d < 64; d++) s += ql[gq][d] * kl[gk][d];
        sl[gq][gk] = s * 0.125f;   // 1/sqrt(64)
    }
    __syncthreads();
    if (tid < 32) {
        float m = -1e30f;
        for (int k2 = 0; k2 < 32; k2++) m = fmaxf(m, sl[tid][k2]);
        float s = 0.f;
        for (int k2 = 0; k2 < 32; k2++) { float e = __expf(sl[tid][k2] - m); sl[tid][k2] = e; s += e; }
        float r = 1.0f / s;
        for (int k2 = 0; k2 < 32; k2++) sl[tid][k2] *= r;
    }
    __syncthreads();
#pragma unroll
    for (int j = 0; j < 8; j++) {
        int idx = j * 256 + tid;
        int g = idx >> 6, d = idx & 63;
        float a = 0.f;
        for (int k2 = 0; k2 < 32; k2++) a += sl[g][k2] * vl[k2][d];
        out_slice[(size_t)bh * 2048 + idx] = a;
    }
}

// ---------------- kZ: ZTf[b][ch][tile][lane][8] = frag-order (os@Wout)^T --
__global__ __launch_bounds__(256) void kZ(
    const float* __restrict__ os, const float* __restrict__ Wout,
    u16* __restrict__ ZTf)
{
    int b = blockIdx.x, cb = blockIdx.y;   // grid (4, 16)
    int t = threadIdx.x;
    int c = cb * 16 + (t & 15), kq = t >> 4;
    int tile = c >> 4, lm = c & 15;
    for (int k = kq * 16; k < kq * 16 + 16; k++) {
        int h = k >> 5, g = k & 31;
        const float* osr = os + ((size_t)(b * 8 + h)) * 2048 + g * 64;
        float acc = 0.f;
        for (int d = 0; d < 64; d++)
            acc += osr[d] * Wout[(h * 64 + d) * 256 + c];
        int ch = k >> 5, quad = (k >> 3) & 3, jj = k & 7;
        int lane = quad * 16 + lm;
        ZTf[((size_t)((b * 8 + ch) * 16 + tile)) * 512 + lane * 8 + jj] = f2b(acc);
    }
}

// ---------------- launcher ----------------
extern "C" void kernel_launch(void* const* d_in, const int* in_sizes, int n_in,
                              void* d_out, int out_size, void* d_ws, size_t ws_size,
                              hipStream_t stream)
{
    const float* x      = (const float*)d_in[0];
    const float* Wfx    = (const float*)d_in[1];
    const float* bfx    = (const float*)d_in[2];
    const float* Wx     = (const float*)d_in[3];
    const float* bx     = (const float*)d_in[4];
    const float* Wslice = (const float*)d_in[5];
    const float* bslice = (const float*)d_in[6];
    const float* temp   = (const float*)d_in[7];
    const float* Wq     = (const float*)d_in[8];
    const float* Wk     = (const float*)d_in[9];
    const float* Wv     = (const float*)d_in[10];
    const float* Wout   = (const float*)d_in[11];
    const float* bout   = (const float*)d_in[12];

    char* ws = (char*)d_ws;
    size_t off = 0;
    auto alloc = [&](size_t bytes) {
        void* p = ws + off;
        off = (off + bytes + 255) & ~(size_t)255;
        return p;
    };
    u16*   fxT   = (u16*)  alloc((size_t)512 * BNc * 2);   // 64 MiB
    u16*   swb   = (u16*)  alloc((size_t)BNc * 256 * 2);   // 32 MiB
    u16*   swT   = (u16*)  alloc((size_t)1024 * Nc * 2);   // 32 MiB
    float* tp    = (float*)alloc((size_t)1024 * 2048 * 4); // 8 MiB
    float* np    = (float*)alloc(32768 * 4);               // 128 KiB
    float* tl    = (float*)alloc(65536 * 4);               // 256 KiB
    float* osl   = (float*)alloc(65536 * 4);               // 256 KiB
    u16*   ZTf   = (u16*)  alloc(4 * 65536 * 2);           // 512 KiB, chunk-major frag order
    u16*   Ball  = (u16*)  alloc((size_t)768 * 256 * 2);   // WfxT rows 0-511, WxsT 512-767
    u16*   Bfrg  = (u16*)  alloc((size_t)768 * 256 * 2);   // chunk-major frag-ordered Ball
    float* bxs   = (float*)alloc(256 * 4);

    u16* WfxT = Ball;
    u16* WxsT = Ball + (size_t)512 * 256;

    k0_fold<<<257, 256, 0, stream>>>(Wx, Wslice, bx, bslice, WxsT, bxs);
    kprep_wfx<<<512, 256, 0, stream>>>(Wfx, WfxT);
    kfrag<<<96, 256, 0, stream>>>(Ball, Bfrg);

    // fused: fxT = (x @ Wfx + bfx)^T  AND  softmax((x @ Wxs + bxs)/T) -> swb, swT
    kproj<<<2048, 256, 0, stream>>>(x, Bfrg, bfx, bxs, temp, fxT, swb, swT);

    k4_token_mfma<<<dim3(32, 32), 256, 0, stream>>>(swT, fxT, tp, np);
    k4b_reduce<<<256, 256, 0, stream>>>(tp, np, tl);
    k5_attn<<<32, 256, 0, stream>>>(tl, Wq, Wk, Wv, osl);
    kZ<<<dim3(4, 16), 256, 0, stream>>>(osl, Wout, ZTf);

    // out = swb @ ZTf_b^T + bout -> f32 d_out
    kout<<<1024, 256, 0, stream>>>(swb, ZTf, bout, (float*)d_out);
}

// Round 7
// 376.007 us; speedup vs baseline: 1.3910x; 1.0409x over previous
//
#include <hip/hip_runtime.h>

// Physics_Attention_Irregular_Mesh — round 8 (resubmit; r8.0 was an infra
// "container failed twice" with no counters — same signature as r5.0 which
// ran fine on identical resubmit. Kernel re-audited: gload_lds dests
// wave-uniform+aligned, sources in-bounds, dbuf race-free, swizzle XOR
// involution correct.)
// B=4, N=16384, DIM=256, H=8, D=64, G=32, inner=512. f32 I/O.
// r8 changes (r7 post-mortem: kproj 149us at 2 blocks/CU, acc[24]=96 AGPR
// capped occupancy at 2 waves/SIMD; k4 ~100us hidden — direct-global frag
// loads are 16-segment scatters):
//  kproj: N split into 2 col-groups (grid 2048x2) -> acc[12], 4 waves/SIMD;
//         B staged via global_load_lds w16 into double-buffered LDS
//         (2x24KiB, stage-next-before-compute, 1 barrier/chunk).
//  k4   : ky split 64 (K=256/block); A+B staged ONCE per block (48KiB LDS,
//         3 blocks/CU) via global_load_lds with XOR-swizzled SOURCE
//         (linear dest + swizzled read, rule-21) -> conflict-free ds_read.
//  k4b  : sums 64 partials. kout/k5/kZ/preps unchanged.

typedef unsigned short u16;
typedef __attribute__((ext_vector_type(8))) unsigned short ushort8v;
typedef __attribute__((ext_vector_type(4))) unsigned short ushort4v;
typedef __attribute__((ext_vector_type(8))) short short8v;
typedef __attribute__((ext_vector_type(4))) float f32x4;

constexpr int Nc = 16384;
constexpr int BNc = 65536;

__device__ inline float b2f(u16 v) {
    union { unsigned int u; float f; } t; t.u = ((unsigned int)v) << 16; return t.f;
}
__device__ inline u16 f2b(float f) {   // round-to-nearest-even
    union { float f; unsigned int u; } t; t.f = f;
    unsigned int u = t.u;
    return (u16)((u + 0x7fffu + ((u >> 16) & 1u)) >> 16);
}

// ---------------- prep: fold WxsT[h*32+g][k] = (Wx_h @ Wslice)^T, bxs ------
__global__ __launch_bounds__(256) void k0_fold(
    const float* __restrict__ Wx, const float* __restrict__ Wslice,
    const float* __restrict__ bx, const float* __restrict__ bslice,
    u16* __restrict__ WxsT, float* __restrict__ bxs)
{
    int blk = blockIdx.x, tid = threadIdx.x;
    int h = tid >> 5, g = tid & 31;
    if (blk < 256) {
        int k = blk;
        float acc = 0.f;
        for (int d = 0; d < 64; d++)
            acc += Wx[k * 512 + h * 64 + d] * Wslice[d * 32 + g];
        WxsT[tid * 256 + k] = f2b(acc);
    } else {
        float acc = 0.f;
        for (int d = 0; d < 64; d++)
            acc += bx[h * 64 + d] * Wslice[d * 32 + g];
        bxs[tid] = acc + bslice[g];
    }
}

// ---------------- prep: WfxT[n][k] bf16 ----------------
__global__ __launch_bounds__(256) void kprep_wfx(const float* __restrict__ Wfx,
                                                 u16* __restrict__ WfxT)
{
    int n = blockIdx.x, k = threadIdx.x;        // 512 blocks x 256
    WfxT[n * 256 + k] = f2b(Wfx[k * 512 + n]);
}

// ---------------- kfrag: repack Ball -> chunk-major fragment order --------
// Bf[c=0..7][t=0..47][lane=0..63][jj=0..7]: lane (lm,quad) holds
// Ball[t*16+lm][c*32+quad*8+jj]. One chunk c = contiguous 48 KiB.
__global__ __launch_bounds__(256) void kfrag(const u16* __restrict__ Ball,
                                             u16* __restrict__ Bf)
{
    int g = blockIdx.x * 256 + threadIdx.x;   // 96 blocks -> 24576 threads
    int pair = g >> 6, lane = g & 63;
    int t = pair >> 3, c = pair & 7;
    int n = t * 16 + (lane & 15);
    int k = c * 32 + (lane >> 4) * 8;
    ushort8v v = *(const ushort8v*)(Ball + (size_t)n * 256 + k);
    *(ushort8v*)(Bf + (size_t)((c * 48 + t) * 64 + lane) * 8) = v;
}

// ---------------- kproj: fused projection, dbuf gload_lds B ---------------
// Grid (2048, 2) x 256. Block = 32 rows x 24 tiles (col-group cg).
// 4 waves: wr = wave&1 (16-row group), wc = wave>>1 (12-tile group).
// Global tile T = cg*24 + wc*12 + j: T<32 -> fx col T*16.., T>=32 ->
// slice logits st=T-32 (head st>>1, g-half st&1). Per chunk: stage next
// chunk's 24 tiles via global_load_lds (6 x 1KiB per wave, frag-order is
// lane-linear so dest is gload_lds-compatible), compute 12 MFMA from LDS,
// ONE barrier. A direct-global with register prefetch.
__global__ __launch_bounds__(256, 4) void kproj(
    const float* __restrict__ x, const u16* __restrict__ Bf,
    const float* __restrict__ bfx, const float* __restrict__ bxs,
    const float* __restrict__ temp,
    u16* __restrict__ fxT, u16* __restrict__ swb, u16* __restrict__ swT)
{
    __shared__ u16 Bs[2][12288];    // 2 x 24 KiB double buffer
    int tid = threadIdx.x;
    int wave = tid >> 6, lane = tid & 63;
    int lm = lane & 15, quad = lane >> 4;
    int wr = wave & 1, wc = wave >> 1;
    int cg = blockIdx.y;
    int row0 = blockIdx.x * 32;
    int arow = row0 + wr * 16 + lm;

    const float* Aptr = x + (size_t)arow * 256 + quad * 8;
    // per-lane global source base for this wave's 6 staging tiles
    const u16* BfW = Bf + (size_t)cg * 12288 + (size_t)(wave * 6) * 512 + lane * 8;

    f32x4 acc[12] = {};
    f32x4 a0 = *(const f32x4*)(Aptr);
    f32x4 a1 = *(const f32x4*)(Aptr + 4);

    // prologue: stage chunk 0 -> buf 0
#pragma unroll
    for (int i = 0; i < 6; i++)
        __builtin_amdgcn_global_load_lds((const uint32_t*)(BfW + i * 512),
                                         (uint32_t*)(&Bs[0][(wave * 6 + i) * 512]),
                                         16, 0, 0);
    __syncthreads();

    int cur = 0;
    for (int c = 0; c < 8; c++) {
        if (c < 7) {   // stage chunk c+1 into the other buffer (in flight over compute)
            const u16* src = BfW + (size_t)(c + 1) * 24576;
            u16* dst = &Bs[cur ^ 1][(wave * 6) * 512];
#pragma unroll
            for (int i = 0; i < 6; i++)
                __builtin_amdgcn_global_load_lds((const uint32_t*)(src + i * 512),
                                                 (uint32_t*)(dst + i * 512), 16, 0, 0);
        }
        ushort8v au;
#pragma unroll
        for (int j = 0; j < 4; j++) { au[j] = f2b(a0[j]); au[4 + j] = f2b(a1[j]); }
        short8v af = (short8v&)au;
        if (c < 7) {               // prefetch next chunk's A
            a0 = *(const f32x4*)(Aptr + c * 32 + 32);
            a1 = *(const f32x4*)(Aptr + c * 32 + 36);
        }
#pragma unroll
        for (int j = 0; j < 12; j++) {
            short8v bf = *(short8v*)&Bs[cur][(wc * 12 + j) * 512 + lane * 8];
            acc[j] = __builtin_amdgcn_mfma_f32_16x16x32_bf16(af, bf, acc[j], 0, 0, 0);
        }
        __syncthreads();           // drains next-chunk stage + read-done of cur
        cur ^= 1;
    }

    // ---- epilogue: fx part ----
    int nbase = row0 + wr * 16 + quad * 4;
    int tbase = cg * 24 + wc * 12;
    int nfx = (cg == 0) ? 12 : (wc == 0 ? 8 : 0);
#pragma unroll
    for (int j = 0; j < 12; j++) {
        if (j < nfx) {
            int cc = (tbase + j) * 16 + lm;
            float bv = bfx[cc];
            ushort4v o;
#pragma unroll
            for (int r = 0; r < 4; r++) o[r] = f2b(acc[j][r] + bv);
            *(ushort4v*)(fxT + (size_t)cc * 65536 + nbase) = o;
        }
    }

    // ---- epilogue: slice softmax (cg==1; wc0 -> heads 0-1, wc1 -> 2-7) ----
    if (cg == 1) {
        int b = row0 >> 14;
        int nlbase = (row0 & 16383) + wr * 16 + quad * 4;
        int nh = wc ? 6 : 2, h0 = wc ? 2 : 0, jb = wc ? 0 : 8;
#pragma unroll
        for (int hh = 0; hh < 6; hh++) {
            if (hh < nh) {
                int h = h0 + hh;
                float it = 1.0f / temp[h];
                float bv0 = bxs[h * 32 + lm];
                float bv1 = bxs[h * 32 + 16 + lm];
                f32x4 A0 = acc[jb + 2 * hh];
                f32x4 A1 = acc[jb + 2 * hh + 1];
                ushort4v p0, p1;
#pragma unroll
                for (int r = 0; r < 4; r++) {
                    float v0 = (A0[r] + bv0) * it;       // g = lm
                    float v1 = (A1[r] + bv1) * it;       // g = 16+lm
                    float m = fmaxf(v0, v1);
                    m = fmaxf(m, __shfl_xor(m, 1));
                    m = fmaxf(m, __shfl_xor(m, 2));
                    m = fmaxf(m, __shfl_xor(m, 4));
                    m = fmaxf(m, __shfl_xor(m, 8));
                    float e0 = __expf(v0 - m), e1 = __expf(v1 - m);
                    float s = e0 + e1;
                    s += __shfl_xor(s, 1);
                    s += __shfl_xor(s, 2);
                    s += __shfl_xor(s, 4);
                    s += __shfl_xor(s, 8);
                    float rs = 1.0f / s;
                    float w0 = e0 * rs, w1 = e1 * rs;
                    int row = row0 + wr * 16 + quad * 4 + r;
                    swb[(size_t)row * 256 + h * 32 + lm] = f2b(w0);
                    swb[(size_t)row * 256 + h * 32 + 16 + lm] = f2b(w1);
                    p0[r] = f2b(w0); p1[r] = f2b(w1);
                }
                size_t gbase = (size_t)((b * 8 + h) * 32);
                *(ushort4v*)(swT + (gbase + lm) * 16384 + nlbase) = p0;
                *(ushort4v*)(swT + (gbase + 16 + lm) * 16384 + nlbase) = p1;
            }
        }
    }
}

// ---------------- kout: out = swb @ ZTf_b^T + bout, LDS-staged B ----------
// ZTf is chunk-major: [b][c=0..7][tile=0..15][lane][8]. Per chunk stage
// 16 KiB (4 tiles per wave), barrier, 16 ds_read+MFMA, barrier.
__global__ __launch_bounds__(256, 4) void kout(
    const u16* __restrict__ swb, const u16* __restrict__ ZTf,
    const float* __restrict__ bout, float* __restrict__ out)
{
    __shared__ u16 Bs[16 * 512];    // 16 KiB
    int tid = threadIdx.x;
    int wave = tid >> 6, lane = tid & 63;
    int lm = lane & 15, quad = lane >> 4;
    int row0 = blockIdx.x * 64;

    const u16* Abase = swb + (size_t)(row0 + wave * 16 + lm) * 256 + quad * 8;
    const u16* Zb    = ZTf + (size_t)(row0 >> 14) * 65536;

    f32x4 acc[16] = {};
    short8v af = *(const short8v*)(Abase);
    for (int c = 0; c < 8; c++) {
        const u16* src = Zb + (size_t)c * 8192 + (size_t)(wave * 4) * 512 + lane * 8;
#pragma unroll
        for (int i = 0; i < 4; i++) {
            ushort8v v = *(const ushort8v*)(src + i * 512);
            *(ushort8v*)&Bs[(wave * 4 + i) * 512 + lane * 8] = v;
        }
        short8v a_cur = af;
        if (c < 7) af = *(const short8v*)(Abase + c * 32 + 32);   // prefetch
        __syncthreads();
#pragma unroll
        for (int j = 0; j < 16; j++) {
            short8v bf = *(short8v*)&Bs[j * 512 + lane * 8];
            acc[j] = __builtin_amdgcn_mfma_f32_16x16x32_bf16(a_cur, bf, acc[j], 0, 0, 0);
        }
        __syncthreads();
    }
#pragma unroll
    for (int j = 0; j < 16; j++) {
        int cc = j * 16 + lm;
        float bv = bout[cc];
#pragma unroll
        for (int r = 0; r < 4; r++)
            out[(size_t)(row0 + wave * 16 + quad * 4 + r) * 256 + cc] = acc[j][r] + bv;
    }
}

// ---------------- k4: token pooling, LDS-staged (swizzled), split-K -------
// Grid (32 bh, 64 ky). Per block: A = swT[bh*32..+32][ky*256..+256] (16KiB),
// B = fxT[h*64..+64][b*16384+ky*256..+256] (32KiB), staged ONCE via
// global_load_lds with XOR-swizzled source (LDS[row][b] = glob[row][b^sw(row)],
// sw(row) = (row&7)<<4 bytes); reads apply the same XOR -> conflict-free.
__global__ __launch_bounds__(256, 4) void k4_token_mfma(
    const u16* __restrict__ swT, const u16* __restrict__ fxT,
    float* __restrict__ token_part, float* __restrict__ norm_part)
{
    __shared__ u16 As[32 * 256];     // 16 KiB
    __shared__ u16 Bs_[64 * 256];    // 32 KiB
    int bh = blockIdx.x, ky = blockIdx.y;
    int b = bh >> 3, h = bh & 7;
    int tid = threadIdx.x, wave = tid >> 6, lane = tid & 63;
    int lm = lane & 15, quad = lane >> 4;
    int mt = wave & 1, dp = wave >> 1;
    int lh = lane >> 5, lb = lane & 31;

#pragma unroll
    for (int i = 0; i < 4; i++) {
        int s = wave * 4 + i;                  // 0..15 -> rows 2s, 2s+1
        int r = 2 * s + lh;
        int sw = ((lb * 16) ^ ((r & 7) << 4)) >> 1;   // u16 offset in row
        const u16* src = swT + (size_t)(bh * 32 + r) * 16384 + ky * 256 + sw;
        __builtin_amdgcn_global_load_lds((const uint32_t*)src,
                                         (uint32_t*)(&As[s * 512]), 16, 0, 0);
    }
#pragma unroll
    for (int i = 0; i < 8; i++) {
        int s = wave * 8 + i;                  // 0..31 -> rows 2s, 2s+1
        int r = 2 * s + lh;
        int sw = ((lb * 16) ^ ((r & 7) << 4)) >> 1;
        const u16* src = fxT + (size_t)(h * 64 + r) * 65536 + (size_t)b * 16384
                         + ky * 256 + sw;
        __builtin_amdgcn_global_load_lds((const uint32_t*)src,
                                         (uint32_t*)(&Bs_[s * 512]), 16, 0, 0);
    }
    __syncthreads();

    int rA = mt * 16 + lm;
    int rB0 = dp * 32 + lm, rB1 = rB0 + 16;
    const char* Ab  = (const char*)As  + rA  * 512;
    const char* Bb0 = (const char*)Bs_ + rB0 * 512;
    const char* Bb1 = (const char*)Bs_ + rB1 * 512;
    int swA  = (rA  & 7) << 4;
    int swB0 = (rB0 & 7) << 4;
    int swB1 = (rB1 & 7) << 4;

    f32x4 acc0 = {}, acc1 = {};
    float nacc = 0.f;
#pragma unroll
    for (int kk = 0; kk < 8; kk++) {
        int base = kk * 64 + quad * 16;
        short8v af = *(const short8v*)(Ab  + (base ^ swA));
        short8v b0 = *(const short8v*)(Bb0 + (base ^ swB0));
        short8v b1 = *(const short8v*)(Bb1 + (base ^ swB1));
        acc0 = __builtin_amdgcn_mfma_f32_16x16x32_bf16(af, b0, acc0, 0, 0, 0);
        acc1 = __builtin_amdgcn_mfma_f32_16x16x32_bf16(af, b1, acc1, 0, 0, 0);
        if (dp == 0) {
            ushort8v au = (ushort8v&)af;
#pragma unroll
            for (int j = 0; j < 8; j++) nacc += b2f(au[j]);
        }
    }
    float* tp = token_part + ((size_t)(ky * 32 + bh)) * 2048;
#pragma unroll
    for (int r = 0; r < 4; r++) {
        int g = mt * 16 + quad * 4 + r;
        tp[g * 64 + dp * 32 + lm] = acc0[r];
        tp[g * 64 + dp * 32 + 16 + lm] = acc1[r];
    }
    if (dp == 0) {
        nacc += __shfl_xor(nacc, 16);
        nacc += __shfl_xor(nacc, 32);
        if (lane < 16)
            norm_part[(ky * 32 + bh) * 32 + mt * 16 + lm] = nacc;
    }
}

// ---------------- k4b: reduce partials -> tl = token/(norm+1e-5) ----------
__global__ __launch_bounds__(256) void k4b_reduce(
    const float* __restrict__ tp, const float* __restrict__ np,
    float* __restrict__ tl)
{
    int t = blockIdx.x * 256 + threadIdx.x;   // 65536
    int bh = t >> 11, e = t & 2047, g = e >> 6;
    float ts = 0.f, ns = 0.f;
    for (int ch = 0; ch < 64; ch++) {
        ts += tp[((size_t)(ch * 32 + bh)) * 2048 + e];
        ns += np[(ch * 32 + bh) * 32 + g];
    }
    tl[t] = ts / (ns + 1e-5f);
}

// ---------------- k5: tiny attention over G tokens ----------------
__global__ __launch_bounds__(256) void k5_attn(
    const float* __restrict__ tlg,
    const float* __restrict__ Wq, const float* __restrict__ Wk, const float* __restrict__ Wv,
    float* __restrict__ out_slice)
{
    __shared__ float tl[32][64];
    __shared__ float ql[32][64], kl[32][64], vl[32][64];
    __shared__ float sl[32][33];
    int bh = blockIdx.x, tid = threadIdx.x;
    const float* tk = tlg + (size_t)bh * 2048;

#pragma unroll
    for (int j = 0; j < 8; j++) {
        int idx = j * 256 + tid;
        tl[idx >> 6][idx & 63] = tk[idx];
    }
    __syncthreads();
#pragma unroll
    for (int j = 0; j < 8; j++) {
        int idx = j * 256 + tid;
        int g = idx >> 6, d = idx & 63;
        float aq = 0.f, ak = 0.f, av = 0.f;
        for (int e = 0; e < 64; e++) {
            float t = tl[g][e];
            aq += t * Wq[e * 64 + d];
            ak += t * Wk[e * 64 + d];
            av += t * Wv[e * 64 + d];
        }
        ql[g][d] = aq; kl[g][d] = ak; vl[g][d] = av;
    }
    __syncthreads();
#pragma unroll
    for (int j = 0; j < 4; j++) {
        int idx = j * 256 + tid;
        int gq = idx >> 5, gk = idx & 31;
        float s = 0.f;
        for (int d = 0; d < 64; d++) s += ql[gq][d] * kl[gk][d];
        sl[gq][gk] = s * 0.125f;   // 1/sqrt(64)
    }
    __syncthreads();
    if (tid < 32) {
        float m = -1e30f;
        for (int k2 = 0; k2 < 32; k2++) m = fmaxf(m, sl[tid][k2]);
        float s = 0.f;
        for (int k2 = 0; k2 < 32; k2++) { float e = __expf(sl[tid][k2] - m); sl[tid][k2] = e; s += e; }
        float r = 1.0f / s;
        for (int k2 = 0; k2 < 32; k2++) sl[tid][k2] *= r;
    }
    __syncthreads();
#pragma unroll
    for (int j = 0; j < 8; j++) {
        int idx = j * 256 + tid;
        int g = idx >> 6, d = idx & 63;
        float a = 0.f;
        for (int k2 = 0; k2 < 32; k2++) a += sl[g][k2] * vl[k2][d];
        out_slice[(size_t)bh * 2048 + idx] = a;
    }
}

// ---------------- kZ: ZTf[b][ch][tile][lane][8] = frag-order (os@Wout)^T --
__global__ __launch_bounds__(256) void kZ(
    const float* __restrict__ os, const float* __restrict__ Wout,
    u16* __restrict__ ZTf)
{
    int b = blockIdx.x, cb = blockIdx.y;   // grid (4, 16)
    int t = threadIdx.x;
    int c = cb * 16 + (t & 15), kq = t >> 4;
    int tile = c >> 4, lm = c & 15;
    for (int k = kq * 16; k < kq * 16 + 16; k++) {
        int h = k >> 5, g = k & 31;
        const float* osr = os + ((size_t)(b * 8 + h)) * 2048 + g * 64;
        float acc = 0.f;
        for (int d = 0; d < 64; d++)
            acc += osr[d] * Wout[(h * 64 + d) * 256 + c];
        int ch = k >> 5, quad = (k >> 3) & 3, jj = k & 7;
        int lane = quad * 16 + lm;
        ZTf[((size_t)((b * 8 + ch) * 16 + tile)) * 512 + lane * 8 + jj] = f2b(acc);
    }
}

// ---------------- launcher ----------------
extern "C" void kernel_launch(void* const* d_in, const int* in_sizes, int n_in,
                              void* d_out, int out_size, void* d_ws, size_t ws_size,
                              hipStream_t stream)
{
    const float* x      = (const float*)d_in[0];
    const float* Wfx    = (const float*)d_in[1];
    const float* bfx    = (const float*)d_in[2];
    const float* Wx     = (const float*)d_in[3];
    const float* bx     = (const float*)d_in[4];
    const float* Wslice = (const float*)d_in[5];
    const float* bslice = (const float*)d_in[6];
    const float* temp   = (const float*)d_in[7];
    const float* Wq     = (const float*)d_in[8];
    const float* Wk     = (const float*)d_in[9];
    const float* Wv     = (const float*)d_in[10];
    const float* Wout   = (const float*)d_in[11];
    const float* bout   = (const float*)d_in[12];

    char* ws = (char*)d_ws;
    size_t off = 0;
    auto alloc = [&](size_t bytes) {
        void* p = ws + off;
        off = (off + bytes + 255) & ~(size_t)255;
        return p;
    };
    u16*   fxT   = (u16*)  alloc((size_t)512 * BNc * 2);   // 64 MiB
    u16*   swb   = (u16*)  alloc((size_t)BNc * 256 * 2);   // 32 MiB
    u16*   swT   = (u16*)  alloc((size_t)1024 * Nc * 2);   // 32 MiB
    float* tp    = (float*)alloc((size_t)2048 * 2048 * 4); // 16 MiB (64 ky x 32 bh)
    float* np    = (float*)alloc((size_t)2048 * 32 * 4);   // 256 KiB
    float* tl    = (float*)alloc(65536 * 4);               // 256 KiB
    float* osl   = (float*)alloc(65536 * 4);               // 256 KiB
    u16*   ZTf   = (u16*)  alloc(4 * 65536 * 2);           // 512 KiB, chunk-major frag order
    u16*   Ball  = (u16*)  alloc((size_t)768 * 256 * 2);   // WfxT rows 0-511, WxsT 512-767
    u16*   Bfrg  = (u16*)  alloc((size_t)768 * 256 * 2);   // chunk-major frag-ordered Ball
    float* bxs   = (float*)alloc(256 * 4);

    u16* WfxT = Ball;
    u16* WxsT = Ball + (size_t)512 * 256;

    k0_fold<<<257, 256, 0, stream>>>(Wx, Wslice, bx, bslice, WxsT, bxs);
    kprep_wfx<<<512, 256, 0, stream>>>(Wfx, WfxT);
    kfrag<<<96, 256, 0, stream>>>(Ball, Bfrg);

    // fused: fxT = (x @ Wfx + bfx)^T  AND  softmax((x @ Wxs + bxs)/T) -> swb, swT
    kproj<<<dim3(2048, 2), 256, 0, stream>>>(x, Bfrg, bfx, bxs, temp, fxT, swb, swT);

    k4_token_mfma<<<dim3(32, 64), 256, 0, stream>>>(swT, fxT, tp, np);
    k4b_reduce<<<256, 256, 0, stream>>>(tp, np, tl);
    k5_attn<<<32, 256, 0, stream>>>(tl, Wq, Wk, Wv, osl);
    kZ<<<dim3(4, 16), 256, 0, stream>>>(osl, Wout, ZTf);

    // out = swb @ ZTf_b^T + bout -> f32 d_out
    kout<<<1024, 256, 0, stream>>>(swb, ZTf, bout, (float*)d_out);
}

// Round 8
// 338.507 us; speedup vs baseline: 1.5451x; 1.1108x over previous
//
#include <hip/hip_runtime.h>

// Physics_Attention_Irregular_Mesh — round 9
// B=4, N=16384, DIM=256, H=8, D=64, G=32, inner=512. f32 I/O.
// r9: kproj made BARRIER-FREE. r8 counters (141us, MfmaUtil 7.3%, occ 29%)
// showed the per-chunk barrier+vmcnt(0) drain dominates: only ~100cyc of
// MFMA per ~700cyc phase. Fix: each wave holds its whole B panel in regs
// (2 tiles x 8 chunks = 64 VGPR, loaded once from L2 in frag order); A
// staged once to XOR-swizzled LDS (16 KiB); ONE barrier per block, then
// 8 x {2 broadcast ds_read_b128 + 4 MFMA} with no syncs.
// Geometry: 512 thr / 8 waves; wave = 2 tiles x 32 rows; grid (2048, 3);
// tile-group 2 == the 16 softmax tiles -> wave q owns pair (32+2q,33+2q).
//   k4 / k4b / kout / k5 / kZ / preps: unchanged from r8 (passed, 3.05e-05).

typedef unsigned short u16;
typedef __attribute__((ext_vector_type(8))) unsigned short ushort8v;
typedef __attribute__((ext_vector_type(4))) unsigned short ushort4v;
typedef __attribute__((ext_vector_type(8))) short short8v;
typedef __attribute__((ext_vector_type(4))) float f32x4;

constexpr int Nc = 16384;
constexpr int BNc = 65536;

__device__ inline float b2f(u16 v) {
    union { unsigned int u; float f; } t; t.u = ((unsigned int)v) << 16; return t.f;
}
__device__ inline u16 f2b(float f) {   // round-to-nearest-even
    union { float f; unsigned int u; } t; t.f = f;
    unsigned int u = t.u;
    return (u16)((u + 0x7fffu + ((u >> 16) & 1u)) >> 16);
}

// ---------------- prep: fold WxsT[h*32+g][k] = (Wx_h @ Wslice)^T, bxs ------
__global__ __launch_bounds__(256) void k0_fold(
    const float* __restrict__ Wx, const float* __restrict__ Wslice,
    const float* __restrict__ bx, const float* __restrict__ bslice,
    u16* __restrict__ WxsT, float* __restrict__ bxs)
{
    int blk = blockIdx.x, tid = threadIdx.x;
    int h = tid >> 5, g = tid & 31;
    if (blk < 256) {
        int k = blk;
        float acc = 0.f;
        for (int d = 0; d < 64; d++)
            acc += Wx[k * 512 + h * 64 + d] * Wslice[d * 32 + g];
        WxsT[tid * 256 + k] = f2b(acc);
    } else {
        float acc = 0.f;
        for (int d = 0; d < 64; d++)
            acc += bx[h * 64 + d] * Wslice[d * 32 + g];
        bxs[tid] = acc + bslice[g];
    }
}

// ---------------- prep: WfxT[n][k] bf16 ----------------
__global__ __launch_bounds__(256) void kprep_wfx(const float* __restrict__ Wfx,
                                                 u16* __restrict__ WfxT)
{
    int n = blockIdx.x, k = threadIdx.x;        // 512 blocks x 256
    WfxT[n * 256 + k] = f2b(Wfx[k * 512 + n]);
}

// ---------------- kfrag: repack Ball -> chunk-major fragment order --------
// Bf[c=0..7][t=0..47][lane=0..63][jj=0..7]: lane (lm,quad) holds
// Ball[t*16+lm][c*32+quad*8+jj]. One chunk c = contiguous 48 KiB.
__global__ __launch_bounds__(256) void kfrag(const u16* __restrict__ Ball,
                                             u16* __restrict__ Bf)
{
    int g = blockIdx.x * 256 + threadIdx.x;   // 96 blocks -> 24576 threads
    int pair = g >> 6, lane = g & 63;
    int t = pair >> 3, c = pair & 7;
    int n = t * 16 + (lane & 15);
    int k = c * 32 + (lane >> 4) * 8;
    ushort8v v = *(const ushort8v*)(Ball + (size_t)n * 256 + k);
    *(ushort8v*)(Bf + (size_t)((c * 48 + t) * 64 + lane) * 8) = v;
}

// ---------------- kproj: fused projection, barrier-free (B in regs) -------
// Grid (2048, 3) x 512. Block = 32 rows x 16 tiles (tile-group tg).
// Wave q owns tiles {tg*16+2q, tg*16+2q+1} x 32 rows (2 row-frags).
// B: 16 frags in VGPRs, loaded once (frag-order, L2-resident).
// A: 32x256 bf16 in LDS, XOR-swizzled rows, staged once -> ONE barrier.
// Inner: 8 chunks x {2 ds_read_b128 (A, broadcast) + 4 MFMA}. No syncs.
__global__ __launch_bounds__(512, 4) void kproj(
    const float* __restrict__ x, const u16* __restrict__ Bf,
    const float* __restrict__ bfx, const float* __restrict__ bxs,
    const float* __restrict__ temp,
    u16* __restrict__ fxT, u16* __restrict__ swb, u16* __restrict__ swT)
{
    __shared__ u16 As[32 * 256];   // 16 KiB bf16, row-XOR-swizzled
    int tid = threadIdx.x;
    int wave = tid >> 6, lane = tid & 63;
    int lm = lane & 15, quad = lane >> 4;
    int tg = blockIdx.y;
    int row0 = blockIdx.x * 32;
    int T0 = tg * 16 + 2 * wave;           // wave's tile pair T0, T0+1

    // ---- issue B-frag loads: 16 x 16B/lane, coalesced, L2-resident ----
    short8v breg0[8], breg1[8];
#pragma unroll
    for (int c = 0; c < 8; c++) {
        breg0[c] = *(const short8v*)(Bf + (size_t)((c * 48 + T0) * 64 + lane) * 8);
        breg1[c] = *(const short8v*)(Bf + (size_t)((c * 48 + T0 + 1) * 64 + lane) * 8);
    }

    // ---- stage A: 32 rows x 256 f32 -> bf16 LDS (swizzled), once ----
    {
        int row = tid >> 4, colg = tid & 15;       // 512 thr: 64B f32 each
        const f32x4* src = (const f32x4*)(x + (size_t)(row0 + row) * 256 + colg * 16);
        f32x4 v0 = src[0], v1 = src[1], v2 = src[2], v3 = src[3];
        ushort8v o0, o1;
#pragma unroll
        for (int j = 0; j < 4; j++) {
            o0[j] = f2b(v0[j]); o0[4 + j] = f2b(v1[j]);
            o1[j] = f2b(v2[j]); o1[4 + j] = f2b(v3[j]);
        }
        int sw = (row & 7) << 4;
        char* base = (char*)As + row * 512;
        *(ushort8v*)(base + ((colg * 32) ^ sw)) = o0;
        *(ushort8v*)(base + ((colg * 32 + 16) ^ sw)) = o1;
    }
    __syncthreads();               // the ONLY barrier

    // ---- main: 8 chunks x {2 A ds_reads + 4 MFMA}, B from regs ----
    f32x4 acc00 = {}, acc01 = {}, acc10 = {}, acc11 = {};
    int swl = (lm & 7) << 4;
    const char* Arow0 = (const char*)As + lm * 512;          // rf=0 row
    const char* Arow1 = (const char*)As + (16 + lm) * 512;   // rf=1 row
#pragma unroll
    for (int c = 0; c < 8; c++) {
        int off = (c * 64 + quad * 16) ^ swl;
        short8v af0 = *(const short8v*)(Arow0 + off);
        short8v af1 = *(const short8v*)(Arow1 + off);
        acc00 = __builtin_amdgcn_mfma_f32_16x16x32_bf16(af0, breg0[c], acc00, 0, 0, 0);
        acc10 = __builtin_amdgcn_mfma_f32_16x16x32_bf16(af1, breg0[c], acc10, 0, 0, 0);
        acc01 = __builtin_amdgcn_mfma_f32_16x16x32_bf16(af0, breg1[c], acc01, 0, 0, 0);
        acc11 = __builtin_amdgcn_mfma_f32_16x16x32_bf16(af1, breg1[c], acc11, 0, 0, 0);
    }

    // ---- epilogue ----
    if (tg < 2) {
        // pure fx tiles
        int nbase = row0 + quad * 4;
#pragma unroll
        for (int i = 0; i < 2; i++) {
            int cc = (T0 + i) * 16 + lm;
            float bv = bfx[cc];
            const f32x4& a0 = i ? acc01 : acc00;
            const f32x4& a1 = i ? acc11 : acc10;
            ushort4v o0, o1;
#pragma unroll
            for (int r = 0; r < 4; r++) { o0[r] = f2b(a0[r] + bv); o1[r] = f2b(a1[r] + bv); }
            *(ushort4v*)(fxT + (size_t)cc * 65536 + nbase) = o0;
            *(ushort4v*)(fxT + (size_t)cc * 65536 + nbase + 16) = o1;
        }
    } else {
        // softmax tiles: wave q = head q; acc*0 -> g=lm, acc*1 -> g=16+lm
        int h = wave;
        int b = row0 >> 14;
        float it = 1.0f / temp[h];
        float bv0 = bxs[h * 32 + lm];
        float bv1 = bxs[h * 32 + 16 + lm];
        size_t gbase = (size_t)((b * 8 + h) * 32);
#pragma unroll
        for (int rf = 0; rf < 2; rf++) {
            const f32x4& A0 = rf ? acc10 : acc00;
            const f32x4& A1 = rf ? acc11 : acc01;
            int nlbase = (row0 & 16383) + rf * 16 + quad * 4;
            ushort4v p0, p1;
#pragma unroll
            for (int r = 0; r < 4; r++) {
                float v0 = (A0[r] + bv0) * it;       // g = lm
                float v1 = (A1[r] + bv1) * it;       // g = 16+lm
                float m = fmaxf(v0, v1);
                m = fmaxf(m, __shfl_xor(m, 1));
                m = fmaxf(m, __shfl_xor(m, 2));
                m = fmaxf(m, __shfl_xor(m, 4));
                m = fmaxf(m, __shfl_xor(m, 8));
                float e0 = __expf(v0 - m), e1 = __expf(v1 - m);
                float s = e0 + e1;
                s += __shfl_xor(s, 1);
                s += __shfl_xor(s, 2);
                s += __shfl_xor(s, 4);
                s += __shfl_xor(s, 8);
                float rs = 1.0f / s;
                float w0 = e0 * rs, w1 = e1 * rs;
                int row = row0 + rf * 16 + quad * 4 + r;
                swb[(size_t)row * 256 + h * 32 + lm] = f2b(w0);
                swb[(size_t)row * 256 + h * 32 + 16 + lm] = f2b(w1);
                p0[r] = f2b(w0); p1[r] = f2b(w1);
            }
            *(ushort4v*)(swT + (gbase + lm) * 16384 + nlbase) = p0;
            *(ushort4v*)(swT + (gbase + 16 + lm) * 16384 + nlbase) = p1;
        }
    }
}

// ---------------- kout: out = swb @ ZTf_b^T + bout, LDS-staged B ----------
// ZTf is chunk-major: [b][c=0..7][tile=0..15][lane][8]. Per chunk stage
// 16 KiB (4 tiles per wave), barrier, 16 ds_read+MFMA, barrier.
__global__ __launch_bounds__(256, 4) void kout(
    const u16* __restrict__ swb, const u16* __restrict__ ZTf,
    const float* __restrict__ bout, float* __restrict__ out)
{
    __shared__ u16 Bs[16 * 512];    // 16 KiB
    int tid = threadIdx.x;
    int wave = tid >> 6, lane = tid & 63;
    int lm = lane & 15, quad = lane >> 4;
    int row0 = blockIdx.x * 64;

    const u16* Abase = swb + (size_t)(row0 + wave * 16 + lm) * 256 + quad * 8;
    const u16* Zb    = ZTf + (size_t)(row0 >> 14) * 65536;

    f32x4 acc[16] = {};
    short8v af = *(const short8v*)(Abase);
    for (int c = 0; c < 8; c++) {
        const u16* src = Zb + (size_t)c * 8192 + (size_t)(wave * 4) * 512 + lane * 8;
#pragma unroll
        for (int i = 0; i < 4; i++) {
            ushort8v v = *(const ushort8v*)(src + i * 512);
            *(ushort8v*)&Bs[(wave * 4 + i) * 512 + lane * 8] = v;
        }
        short8v a_cur = af;
        if (c < 7) af = *(const short8v*)(Abase + c * 32 + 32);   // prefetch
        __syncthreads();
#pragma unroll
        for (int j = 0; j < 16; j++) {
            short8v bf = *(short8v*)&Bs[j * 512 + lane * 8];
            acc[j] = __builtin_amdgcn_mfma_f32_16x16x32_bf16(a_cur, bf, acc[j], 0, 0, 0);
        }
        __syncthreads();
    }
#pragma unroll
    for (int j = 0; j < 16; j++) {
        int cc = j * 16 + lm;
        float bv = bout[cc];
#pragma unroll
        for (int r = 0; r < 4; r++)
            out[(size_t)(row0 + wave * 16 + quad * 4 + r) * 256 + cc] = acc[j][r] + bv;
    }
}

// ---------------- k4: token pooling, LDS-staged (swizzled), split-K -------
// Grid (32 bh, 64 ky). Per block: A = swT[bh*32..+32][ky*256..+256] (16KiB),
// B = fxT[h*64..+64][b*16384+ky*256..+256] (32KiB), staged ONCE via
// global_load_lds with XOR-swizzled source (LDS[row][b] = glob[row][b^sw(row)],
// sw(row) = (row&7)<<4 bytes); reads apply the same XOR -> conflict-free.
__global__ __launch_bounds__(256, 4) void k4_token_mfma(
    const u16* __restrict__ swT, const u16* __restrict__ fxT,
    float* __restrict__ token_part, float* __restrict__ norm_part)
{
    __shared__ u16 As[32 * 256];     // 16 KiB
    __shared__ u16 Bs_[64 * 256];    // 32 KiB
    int bh = blockIdx.x, ky = blockIdx.y;
    int b = bh >> 3, h = bh & 7;
    int tid = threadIdx.x, wave = tid >> 6, lane = tid & 63;
    int lm = lane & 15, quad = lane >> 4;
    int mt = wave & 1, dp = wave >> 1;
    int lh = lane >> 5, lb = lane & 31;

#pragma unroll
    for (int i = 0; i < 4; i++) {
        int s = wave * 4 + i;                  // 0..15 -> rows 2s, 2s+1
        int r = 2 * s + lh;
        int sw = ((lb * 16) ^ ((r & 7) << 4)) >> 1;   // u16 offset in row
        const u16* src = swT + (size_t)(bh * 32 + r) * 16384 + ky * 256 + sw;
        __builtin_amdgcn_global_load_lds((const uint32_t*)src,
                                         (uint32_t*)(&As[s * 512]), 16, 0, 0);
    }
#pragma unroll
    for (int i = 0; i < 8; i++) {
        int s = wave * 8 + i;                  // 0..31 -> rows 2s, 2s+1
        int r = 2 * s + lh;
        int sw = ((lb * 16) ^ ((r & 7) << 4)) >> 1;
        const u16* src = fxT + (size_t)(h * 64 + r) * 65536 + (size_t)b * 16384
                         + ky * 256 + sw;
        __builtin_amdgcn_global_load_lds((const uint32_t*)src,
                                         (uint32_t*)(&Bs_[s * 512]), 16, 0, 0);
    }
    __syncthreads();

    int rA = mt * 16 + lm;
    int rB0 = dp * 32 + lm, rB1 = rB0 + 16;
    const char* Ab  = (const char*)As  + rA  * 512;
    const char* Bb0 = (const char*)Bs_ + rB0 * 512;
    const char* Bb1 = (const char*)Bs_ + rB1 * 512;
    int swA  = (rA  & 7) << 4;
    int swB0 = (rB0 & 7) << 4;
    int swB1 = (rB1 & 7) << 4;

    f32x4 acc0 = {}, acc1 = {};
    float nacc = 0.f;
#pragma unroll
    for (int kk = 0; kk < 8; kk++) {
        int base = kk * 64 + quad * 16;
        short8v af = *(const short8v*)(Ab  + (base ^ swA));
        short8v b0 = *(const short8v*)(Bb0 + (base ^ swB0));
        short8v b1 = *(const short8v*)(Bb1 + (base ^ swB1));
        acc0 = __builtin_amdgcn_mfma_f32_16x16x32_bf16(af, b0, acc0, 0, 0, 0);
        acc1 = __builtin_amdgcn_mfma_f32_16x16x32_bf16(af, b1, acc1, 0, 0, 0);
        if (dp == 0) {
            ushort8v au = (ushort8v&)af;
#pragma unroll
            for (int j = 0; j < 8; j++) nacc += b2f(au[j]);
        }
    }
    float* tp = token_part + ((size_t)(ky * 32 + bh)) * 2048;
#pragma unroll
    for (int r = 0; r < 4; r++) {
        int g = mt * 16 + quad * 4 + r;
        tp[g * 64 + dp * 32 + lm] = acc0[r];
        tp[g * 64 + dp * 32 + 16 + lm] = acc1[r];
    }
    if (dp == 0) {
        nacc += __shfl_xor(nacc, 16);
        nacc += __shfl_xor(nacc, 32);
        if (lane < 16)
            norm_part[(ky * 32 + bh) * 32 + mt * 16 + lm] = nacc;
    }
}

// ---------------- k4b: reduce partials -> tl = token/(norm+1e-5) ----------
__global__ __launch_bounds__(256) void k4b_reduce(
    const float* __restrict__ tp, const float* __restrict__ np,
    float* __restrict__ tl)
{
    int t = blockIdx.x * 256 + threadIdx.x;   // 65536
    int bh = t >> 11, e = t & 2047, g = e >> 6;
    float ts = 0.f, ns = 0.f;
    for (int ch = 0; ch < 64; ch++) {
        ts += tp[((size_t)(ch * 32 + bh)) * 2048 + e];
        ns += np[(ch * 32 + bh) * 32 + g];
    }
    tl[t] = ts / (ns + 1e-5f);
}

// ---------------- k5: tiny attention over G tokens ----------------
__global__ __launch_bounds__(256) void k5_attn(
    const float* __restrict__ tlg,
    const float* __restrict__ Wq, const float* __restrict__ Wk, const float* __restrict__ Wv,
    float* __restrict__ out_slice)
{
    __shared__ float tl[32][64];
    __shared__ float ql[32][64], kl[32][64], vl[32][64];
    __shared__ float sl[32][33];
    int bh = blockIdx.x, tid = threadIdx.x;
    const float* tk = tlg + (size_t)bh * 2048;

#pragma unroll
    for (int j = 0; j < 8; j++) {
        int idx = j * 256 + tid;
        tl[idx >> 6][idx & 63] = tk[idx];
    }
    __syncthreads();
#pragma unroll
    for (int j = 0; j < 8; j++) {
        int idx = j * 256 + tid;
        int g = idx >> 6, d = idx & 63;
        float aq = 0.f, ak = 0.f, av = 0.f;
        for (int e = 0; e < 64; e++) {
            float t = tl[g][e];
            aq += t * Wq[e * 64 + d];
            ak += t * Wk[e * 64 + d];
            av += t * Wv[e * 64 + d];
        }
        ql[g][d] = aq; kl[g][d] = ak; vl[g][d] = av;
    }
    __syncthreads();
#pragma unroll
    for (int j = 0; j < 4; j++) {
        int idx = j * 256 + tid;
        int gq = idx >> 5, gk = idx & 31;
        float s = 0.f;
        for (int d = 0; d < 64; d++) s += ql[gq][d] * kl[gk][d];
        sl[gq][gk] = s * 0.125f;   // 1/sqrt(64)
    }
    __syncthreads();
    if (tid < 32) {
        float m = -1e30f;
        for (int k2 = 0; k2 < 32; k2++) m = fmaxf(m, sl[tid][k2]);
        float s = 0.f;
        for (int k2 = 0; k2 < 32; k2++) { float e = __expf(sl[tid][k2] - m); sl[tid][k2] = e; s += e; }
        float r = 1.0f / s;
        for (int k2 = 0; k2 < 32; k2++) sl[tid][k2] *= r;
    }
    __syncthreads();
#pragma unroll
    for (int j = 0; j < 8; j++) {
        int idx = j * 256 + tid;
        int g = idx >> 6, d = idx & 63;
        float a = 0.f;
        for (int k2 = 0; k2 < 32; k2++) a += sl[g][k2] * vl[k2][d];
        out_slice[(size_t)bh * 2048 + idx] = a;
    }
}

// ---------------- kZ: ZTf[b][ch][tile][lane][8] = frag-order (os@Wout)^T --
__global__ __launch_bounds__(256) void kZ(
    const float* __restrict__ os, const float* __restrict__ Wout,
    u16* __restrict__ ZTf)
{
    int b = blockIdx.x, cb = blockIdx.y;   // grid (4, 16)
    int t = threadIdx.x;
    int c = cb * 16 + (t & 15), kq = t >> 4;
    int tile = c >> 4, lm = c & 15;
    for (int k = kq * 16; k < kq * 16 + 16; k++) {
        int h = k >> 5, g = k & 31;
        const float* osr = os + ((size_t)(b * 8 + h)) * 2048 + g * 64;
        float acc = 0.f;
        for (int d = 0; d < 64; d++)
            acc += osr[d] * Wout[(h * 64 + d) * 256 + c];
        int ch = k >> 5, quad = (k >> 3) & 3, jj = k & 7;
        int lane = quad * 16 + lm;
        ZTf[((size_t)((b * 8 + ch) * 16 + tile)) * 512 + lane * 8 + jj] = f2b(acc);
    }
}

// ---------------- launcher ----------------
extern "C" void kernel_launch(void* const* d_in, const int* in_sizes, int n_in,
                              void* d_out, int out_size, void* d_ws, size_t ws_size,
                              hipStream_t stream)
{
    const float* x      = (const float*)d_in[0];
    const float* Wfx    = (const float*)d_in[1];
    const float* bfx    = (const float*)d_in[2];
    const float* Wx     = (const float*)d_in[3];
    const float* bx     = (const float*)d_in[4];
    const float* Wslice = (const float*)d_in[5];
    const float* bslice = (const float*)d_in[6];
    const float* temp   = (const float*)d_in[7];
    const float* Wq     = (const float*)d_in[8];
    const float* Wk     = (const float*)d_in[9];
    const float* Wv     = (const float*)d_in[10];
    const float* Wout   = (const float*)d_in[11];
    const float* bout   = (const float*)d_in[12];

    char* ws = (char*)d_ws;
    size_t off = 0;
    auto alloc = [&](size_t bytes) {
        void* p = ws + off;
        off = (off + bytes + 255) & ~(size_t)255;
        return p;
    };
    u16*   fxT   = (u16*)  alloc((size_t)512 * BNc * 2);   // 64 MiB
    u16*   swb   = (u16*)  alloc((size_t)BNc * 256 * 2);   // 32 MiB
    u16*   swT   = (u16*)  alloc((size_t)1024 * Nc * 2);   // 32 MiB
    float* tp    = (float*)alloc((size_t)2048 * 2048 * 4); // 16 MiB (64 ky x 32 bh)
    float* np    = (float*)alloc((size_t)2048 * 32 * 4);   // 256 KiB
    float* tl    = (float*)alloc(65536 * 4);               // 256 KiB
    float* osl   = (float*)alloc(65536 * 4);               // 256 KiB
    u16*   ZTf   = (u16*)  alloc(4 * 65536 * 2);           // 512 KiB, chunk-major frag order
    u16*   Ball  = (u16*)  alloc((size_t)768 * 256 * 2);   // WfxT rows 0-511, WxsT 512-767
    u16*   Bfrg  = (u16*)  alloc((size_t)768 * 256 * 2);   // chunk-major frag-ordered Ball
    float* bxs   = (float*)alloc(256 * 4);

    u16* WfxT = Ball;
    u16* WxsT = Ball + (size_t)512 * 256;

    k0_fold<<<257, 256, 0, stream>>>(Wx, Wslice, bx, bslice, WxsT, bxs);
    kprep_wfx<<<512, 256, 0, stream>>>(Wfx, WfxT);
    kfrag<<<96, 256, 0, stream>>>(Ball, Bfrg);

    // fused: fxT = (x @ Wfx + bfx)^T  AND  softmax((x @ Wxs + bxs)/T) -> swb, swT
    kproj<<<dim3(2048, 3), 512, 0, stream>>>(x, Bfrg, bfx, bxs, temp, fxT, swb, swT);

    k4_token_mfma<<<dim3(32, 64), 256, 0, stream>>>(swT, fxT, tp, np);
    k4b_reduce<<<256, 256, 0, stream>>>(tp, np, tl);
    k5_attn<<<32, 256, 0, stream>>>(tl, Wq, Wk, Wv, osl);
    kZ<<<dim3(4, 16), 256, 0, stream>>>(osl, Wout, ZTf);

    // out = swb @ ZTf_b^T + bout -> f32 d_out
    kout<<<1024, 256, 0, stream>>>(swb, ZTf, bout, (float*)d_out);
}

// Round 9
// 336.725 us; speedup vs baseline: 1.5533x; 1.0053x over previous
//
#include <hip/hip_runtime.h>

// Physics_Attention_Irregular_Mesh — round 10
// B=4, N=16384, DIM=256, H=8, D=64, G=32, inner=512. f32 I/O.
// r10 (r9 post-mortem: kproj VGPR=48 proves the compiler SANK the 16 B-frag
// loads into the MFMA loop -> per-chunk L2 latency serialization, 96us):
//  kproj: pin B-panel in regs with sched_barrier(0) after the load loop.
//  kout : rebuilt as the same barrier-free structure (was 16 barriers/block):
//         A=swb staged once to swizzled LDS, B=ZTf pinned in regs, 1 barrier.
//  k4 / k4b / k5 / kZ / preps: unchanged (passed, absmax 3.05e-05).

typedef unsigned short u16;
typedef __attribute__((ext_vector_type(8))) unsigned short ushort8v;
typedef __attribute__((ext_vector_type(4))) unsigned short ushort4v;
typedef __attribute__((ext_vector_type(8))) short short8v;
typedef __attribute__((ext_vector_type(4))) float f32x4;

constexpr int Nc = 16384;
constexpr int BNc = 65536;

__device__ inline float b2f(u16 v) {
    union { unsigned int u; float f; } t; t.u = ((unsigned int)v) << 16; return t.f;
}
__device__ inline u16 f2b(float f) {   // round-to-nearest-even
    union { float f; unsigned int u; } t; t.f = f;
    unsigned int u = t.u;
    return (u16)((u + 0x7fffu + ((u >> 16) & 1u)) >> 16);
}

// ---------------- prep: fold WxsT[h*32+g][k] = (Wx_h @ Wslice)^T, bxs ------
__global__ __launch_bounds__(256) void k0_fold(
    const float* __restrict__ Wx, const float* __restrict__ Wslice,
    const float* __restrict__ bx, const float* __restrict__ bslice,
    u16* __restrict__ WxsT, float* __restrict__ bxs)
{
    int blk = blockIdx.x, tid = threadIdx.x;
    int h = tid >> 5, g = tid & 31;
    if (blk < 256) {
        int k = blk;
        float acc = 0.f;
        for (int d = 0; d < 64; d++)
            acc += Wx[k * 512 + h * 64 + d] * Wslice[d * 32 + g];
        WxsT[tid * 256 + k] = f2b(acc);
    } else {
        float acc = 0.f;
        for (int d = 0; d < 64; d++)
            acc += bx[h * 64 + d] * Wslice[d * 32 + g];
        bxs[tid] = acc + bslice[g];
    }
}

// ---------------- prep: WfxT[n][k] bf16 ----------------
__global__ __launch_bounds__(256) void kprep_wfx(const float* __restrict__ Wfx,
                                                 u16* __restrict__ WfxT)
{
    int n = blockIdx.x, k = threadIdx.x;        // 512 blocks x 256
    WfxT[n * 256 + k] = f2b(Wfx[k * 512 + n]);
}

// ---------------- kfrag: repack Ball -> chunk-major fragment order --------
// Bf[c=0..7][t=0..47][lane=0..63][jj=0..7]: lane (lm,quad) holds
// Ball[t*16+lm][c*32+quad*8+jj]. One chunk c = contiguous 48 KiB.
__global__ __launch_bounds__(256) void kfrag(const u16* __restrict__ Ball,
                                             u16* __restrict__ Bf)
{
    int g = blockIdx.x * 256 + threadIdx.x;   // 96 blocks -> 24576 threads
    int pair = g >> 6, lane = g & 63;
    int t = pair >> 3, c = pair & 7;
    int n = t * 16 + (lane & 15);
    int k = c * 32 + (lane >> 4) * 8;
    ushort8v v = *(const ushort8v*)(Ball + (size_t)n * 256 + k);
    *(ushort8v*)(Bf + (size_t)((c * 48 + t) * 64 + lane) * 8) = v;
}

// ---------------- kproj: fused projection, barrier-free (B in regs) -------
// Grid (2048, 3) x 512. Block = 32 rows x 16 tiles (tile-group tg).
// Wave q owns tiles {tg*16+2q, tg*16+2q+1} x 32 rows (2 row-frags).
// B: 16 frags in VGPRs, loaded once, PINNED via sched_barrier(0).
// A: 32x256 bf16 in LDS, XOR-swizzled rows, staged once -> ONE barrier.
// Inner: 8 chunks x {2 ds_read_b128 (A, broadcast) + 4 MFMA}. No syncs.
__global__ __launch_bounds__(512, 4) void kproj(
    const float* __restrict__ x, const u16* __restrict__ Bf,
    const float* __restrict__ bfx, const float* __restrict__ bxs,
    const float* __restrict__ temp,
    u16* __restrict__ fxT, u16* __restrict__ swb, u16* __restrict__ swT)
{
    __shared__ u16 As[32 * 256];   // 16 KiB bf16, row-XOR-swizzled
    int tid = threadIdx.x;
    int wave = tid >> 6, lane = tid & 63;
    int lm = lane & 15, quad = lane >> 4;
    int tg = blockIdx.y;
    int row0 = blockIdx.x * 32;
    int T0 = tg * 16 + 2 * wave;           // wave's tile pair T0, T0+1

    // ---- issue B-frag loads: 16 x 16B/lane, coalesced, L2-resident ----
    short8v breg0[8], breg1[8];
#pragma unroll
    for (int c = 0; c < 8; c++) {
        breg0[c] = *(const short8v*)(Bf + (size_t)((c * 48 + T0) * 64 + lane) * 8);
        breg1[c] = *(const short8v*)(Bf + (size_t)((c * 48 + T0 + 1) * 64 + lane) * 8);
    }
    // PIN: forbid the scheduler from sinking the B loads into the MFMA loop
    // (r9: compiler sank them -> per-chunk L2 latency, VGPR_Count=48).
    __builtin_amdgcn_sched_barrier(0);

    // ---- stage A: 32 rows x 256 f32 -> bf16 LDS (swizzled), once ----
    {
        int row = tid >> 4, colg = tid & 15;       // 512 thr: 64B f32 each
        const f32x4* src = (const f32x4*)(x + (size_t)(row0 + row) * 256 + colg * 16);
        f32x4 v0 = src[0], v1 = src[1], v2 = src[2], v3 = src[3];
        ushort8v o0, o1;
#pragma unroll
        for (int j = 0; j < 4; j++) {
            o0[j] = f2b(v0[j]); o0[4 + j] = f2b(v1[j]);
            o1[j] = f2b(v2[j]); o1[4 + j] = f2b(v3[j]);
        }
        int sw = (row & 7) << 4;
        char* base = (char*)As + row * 512;
        *(ushort8v*)(base + ((colg * 32) ^ sw)) = o0;
        *(ushort8v*)(base + ((colg * 32 + 16) ^ sw)) = o1;
    }
    __syncthreads();               // the ONLY barrier

    // ---- main: 8 chunks x {2 A ds_reads + 4 MFMA}, B from regs ----
    f32x4 acc00 = {}, acc01 = {}, acc10 = {}, acc11 = {};
    int swl = (lm & 7) << 4;
    const char* Arow0 = (const char*)As + lm * 512;          // rf=0 row
    const char* Arow1 = (const char*)As + (16 + lm) * 512;   // rf=1 row
#pragma unroll
    for (int c = 0; c < 8; c++) {
        int off = (c * 64 + quad * 16) ^ swl;
        short8v af0 = *(const short8v*)(Arow0 + off);
        short8v af1 = *(const short8v*)(Arow1 + off);
        acc00 = __builtin_amdgcn_mfma_f32_16x16x32_bf16(af0, breg0[c], acc00, 0, 0, 0);
        acc10 = __builtin_amdgcn_mfma_f32_16x16x32_bf16(af1, breg0[c], acc10, 0, 0, 0);
        acc01 = __builtin_amdgcn_mfma_f32_16x16x32_bf16(af0, breg1[c], acc01, 0, 0, 0);
        acc11 = __builtin_amdgcn_mfma_f32_16x16x32_bf16(af1, breg1[c], acc11, 0, 0, 0);
    }

    // ---- epilogue ----
    if (tg < 2) {
        // pure fx tiles
        int nbase = row0 + quad * 4;
#pragma unroll
        for (int i = 0; i < 2; i++) {
            int cc = (T0 + i) * 16 + lm;
            float bv = bfx[cc];
            const f32x4& a0 = i ? acc01 : acc00;
            const f32x4& a1 = i ? acc11 : acc10;
            ushort4v o0, o1;
#pragma unroll
            for (int r = 0; r < 4; r++) { o0[r] = f2b(a0[r] + bv); o1[r] = f2b(a1[r] + bv); }
            *(ushort4v*)(fxT + (size_t)cc * 65536 + nbase) = o0;
            *(ushort4v*)(fxT + (size_t)cc * 65536 + nbase + 16) = o1;
        }
    } else {
        // softmax tiles: wave q = head q; acc*0 -> g=lm, acc*1 -> g=16+lm
        int h = wave;
        int b = row0 >> 14;
        float it = 1.0f / temp[h];
        float bv0 = bxs[h * 32 + lm];
        float bv1 = bxs[h * 32 + 16 + lm];
        size_t gbase = (size_t)((b * 8 + h) * 32);
#pragma unroll
        for (int rf = 0; rf < 2; rf++) {
            const f32x4& A0 = rf ? acc10 : acc00;
            const f32x4& A1 = rf ? acc11 : acc01;
            int nlbase = (row0 & 16383) + rf * 16 + quad * 4;
            ushort4v p0, p1;
#pragma unroll
            for (int r = 0; r < 4; r++) {
                float v0 = (A0[r] + bv0) * it;       // g = lm
                float v1 = (A1[r] + bv1) * it;       // g = 16+lm
                float m = fmaxf(v0, v1);
                m = fmaxf(m, __shfl_xor(m, 1));
                m = fmaxf(m, __shfl_xor(m, 2));
                m = fmaxf(m, __shfl_xor(m, 4));
                m = fmaxf(m, __shfl_xor(m, 8));
                float e0 = __expf(v0 - m), e1 = __expf(v1 - m);
                float s = e0 + e1;
                s += __shfl_xor(s, 1);
                s += __shfl_xor(s, 2);
                s += __shfl_xor(s, 4);
                s += __shfl_xor(s, 8);
                float rs = 1.0f / s;
                float w0 = e0 * rs, w1 = e1 * rs;
                int row = row0 + rf * 16 + quad * 4 + r;
                swb[(size_t)row * 256 + h * 32 + lm] = f2b(w0);
                swb[(size_t)row * 256 + h * 32 + 16 + lm] = f2b(w1);
                p0[r] = f2b(w0); p1[r] = f2b(w1);
            }
            *(ushort4v*)(swT + (gbase + lm) * 16384 + nlbase) = p0;
            *(ushort4v*)(swT + (gbase + 16 + lm) * 16384 + nlbase) = p1;
        }
    }
}

// ---------------- kout: out = swb @ ZTf_b^T + bout, barrier-free ----------
// Same structure as kproj: grid 2048 x 512 thr. Block = 32 rows x 16 tiles;
// wave q owns tiles {2q, 2q+1}. B = ZTf frags pinned in regs; A = swb
// staged once to swizzled LDS (bf16, no conversion). ONE barrier.
__global__ __launch_bounds__(512, 4) void kout(
    const u16* __restrict__ swb, const u16* __restrict__ ZTf,
    const float* __restrict__ bout, float* __restrict__ out)
{
    __shared__ u16 As[32 * 256];   // 16 KiB
    int tid = threadIdx.x;
    int wave = tid >> 6, lane = tid & 63;
    int lm = lane & 15, quad = lane >> 4;
    int row0 = blockIdx.x * 32;
    int T0 = 2 * wave;
    int b = row0 >> 14;

    // ---- B-frag loads, pinned ----
    const u16* Zb = ZTf + (size_t)b * 65536;
    short8v breg0[8], breg1[8];
#pragma unroll
    for (int c = 0; c < 8; c++) {
        breg0[c] = *(const short8v*)(Zb + (size_t)((c * 16 + T0) * 64 + lane) * 8);
        breg1[c] = *(const short8v*)(Zb + (size_t)((c * 16 + T0 + 1) * 64 + lane) * 8);
    }
    __builtin_amdgcn_sched_barrier(0);

    // ---- stage A: swb 32 rows x 256 bf16 -> swizzled LDS ----
    {
        int row = tid >> 4, colg = tid & 15;   // 32B per thread
        const ushort8v* src = (const ushort8v*)(swb + (size_t)(row0 + row) * 256 + colg * 16);
        ushort8v v0 = src[0], v1 = src[1];
        int sw = (row & 7) << 4;
        char* base = (char*)As + row * 512;
        *(ushort8v*)(base + ((colg * 32) ^ sw)) = v0;
        *(ushort8v*)(base + ((colg * 32 + 16) ^ sw)) = v1;
    }
    __syncthreads();               // the ONLY barrier

    // ---- main loop ----
    f32x4 acc00 = {}, acc01 = {}, acc10 = {}, acc11 = {};
    int swl = (lm & 7) << 4;
    const char* Arow0 = (const char*)As + lm * 512;
    const char* Arow1 = (const char*)As + (16 + lm) * 512;
#pragma unroll
    for (int c = 0; c < 8; c++) {
        int off = (c * 64 + quad * 16) ^ swl;
        short8v af0 = *(const short8v*)(Arow0 + off);
        short8v af1 = *(const short8v*)(Arow1 + off);
        acc00 = __builtin_amdgcn_mfma_f32_16x16x32_bf16(af0, breg0[c], acc00, 0, 0, 0);
        acc10 = __builtin_amdgcn_mfma_f32_16x16x32_bf16(af1, breg0[c], acc10, 0, 0, 0);
        acc01 = __builtin_amdgcn_mfma_f32_16x16x32_bf16(af0, breg1[c], acc01, 0, 0, 0);
        acc11 = __builtin_amdgcn_mfma_f32_16x16x32_bf16(af1, breg1[c], acc11, 0, 0, 0);
    }

    // ---- epilogue: f32 + bias ----
    int cc0 = T0 * 16 + lm, cc1 = cc0 + 16;
    float bv0 = bout[cc0], bv1 = bout[cc1];
#pragma unroll
    for (int r = 0; r < 4; r++) {
        int rowa = row0 + quad * 4 + r;
        int rowb = rowa + 16;
        out[(size_t)rowa * 256 + cc0] = acc00[r] + bv0;
        out[(size_t)rowa * 256 + cc1] = acc01[r] + bv1;
        out[(size_t)rowb * 256 + cc0] = acc10[r] + bv0;
        out[(size_t)rowb * 256 + cc1] = acc11[r] + bv1;
    }
}

// ---------------- k4: token pooling, LDS-staged (swizzled), split-K -------
// Grid (32 bh, 64 ky). Per block: A = swT[bh*32..+32][ky*256..+256] (16KiB),
// B = fxT[h*64..+64][b*16384+ky*256..+256] (32KiB), staged ONCE via
// global_load_lds with XOR-swizzled source (LDS[row][b] = glob[row][b^sw(row)],
// sw(row) = (row&7)<<4 bytes); reads apply the same XOR -> conflict-free.
__global__ __launch_bounds__(256, 4) void k4_token_mfma(
    const u16* __restrict__ swT, const u16* __restrict__ fxT,
    float* __restrict__ token_part, float* __restrict__ norm_part)
{
    __shared__ u16 As[32 * 256];     // 16 KiB
    __shared__ u16 Bs_[64 * 256];    // 32 KiB
    int bh = blockIdx.x, ky = blockIdx.y;
    int b = bh >> 3, h = bh & 7;
    int tid = threadIdx.x, wave = tid >> 6, lane = tid & 63;
    int lm = lane & 15, quad = lane >> 4;
    int mt = wave & 1, dp = wave >> 1;
    int lh = lane >> 5, lb = lane & 31;

#pragma unroll
    for (int i = 0; i < 4; i++) {
        int s = wave * 4 + i;                  // 0..15 -> rows 2s, 2s+1
        int r = 2 * s + lh;
        int sw = ((lb * 16) ^ ((r & 7) << 4)) >> 1;   // u16 offset in row
        const u16* src = swT + (size_t)(bh * 32 + r) * 16384 + ky * 256 + sw;
        __builtin_amdgcn_global_load_lds((const uint32_t*)src,
                                         (uint32_t*)(&As[s * 512]), 16, 0, 0);
    }
#pragma unroll
    for (int i = 0; i < 8; i++) {
        int s = wave * 8 + i;                  // 0..31 -> rows 2s, 2s+1
        int r = 2 * s + lh;
        int sw = ((lb * 16) ^ ((r & 7) << 4)) >> 1;
        const u16* src = fxT + (size_t)(h * 64 + r) * 65536 + (size_t)b * 16384
                         + ky * 256 + sw;
        __builtin_amdgcn_global_load_lds((const uint32_t*)src,
                                         (uint32_t*)(&Bs_[s * 512]), 16, 0, 0);
    }
    __syncthreads();

    int rA = mt * 16 + lm;
    int rB0 = dp * 32 + lm, rB1 = rB0 + 16;
    const char* Ab  = (const char*)As  + rA  * 512;
    const char* Bb0 = (const char*)Bs_ + rB0 * 512;
    const char* Bb1 = (const char*)Bs_ + rB1 * 512;
    int swA  = (rA  & 7) << 4;
    int swB0 = (rB0 & 7) << 4;
    int swB1 = (rB1 & 7) << 4;

    f32x4 acc0 = {}, acc1 = {};
    float nacc = 0.f;
#pragma unroll
    for (int kk = 0; kk < 8; kk++) {
        int base = kk * 64 + quad * 16;
        short8v af = *(const short8v*)(Ab  + (base ^ swA));
        short8v b0 = *(const short8v*)(Bb0 + (base ^ swB0));
        short8v b1 = *(const short8v*)(Bb1 + (base ^ swB1));
        acc0 = __builtin_amdgcn_mfma_f32_16x16x32_bf16(af, b0, acc0, 0, 0, 0);
        acc1 = __builtin_amdgcn_mfma_f32_16x16x32_bf16(af, b1, acc1, 0, 0, 0);
        if (dp == 0) {
            ushort8v au = (ushort8v&)af;
#pragma unroll
            for (int j = 0; j < 8; j++) nacc += b2f(au[j]);
        }
    }
    float* tp = token_part + ((size_t)(ky * 32 + bh)) * 2048;
#pragma unroll
    for (int r = 0; r < 4; r++) {
        int g = mt * 16 + quad * 4 + r;
        tp[g * 64 + dp * 32 + lm] = acc0[r];
        tp[g * 64 + dp * 32 + 16 + lm] = acc1[r];
    }
    if (dp == 0) {
        nacc += __shfl_xor(nacc, 16);
        nacc += __shfl_xor(nacc, 32);
        if (lane < 16)
            norm_part[(ky * 32 + bh) * 32 + mt * 16 + lm] = nacc;
    }
}

// ---------------- k4b: reduce partials -> tl = token/(norm+1e-5) ----------
__global__ __launch_bounds__(256) void k4b_reduce(
    const float* __restrict__ tp, const float* __restrict__ np,
    float* __restrict__ tl)
{
    int t = blockIdx.x * 256 + threadIdx.x;   // 65536
    int bh = t >> 11, e = t & 2047, g = e >> 6;
    float ts = 0.f, ns = 0.f;
    for (int ch = 0; ch < 64; ch++) {
        ts += tp[((size_t)(ch * 32 + bh)) * 2048 + e];
        ns += np[(ch * 32 + bh) * 32 + g];
    }
    tl[t] = ts / (ns + 1e-5f);
}

// ---------------- k5: tiny attention over G tokens ----------------
__global__ __launch_bounds__(256) void k5_attn(
    const float* __restrict__ tlg,
    const float* __restrict__ Wq, const float* __restrict__ Wk, const float* __restrict__ Wv,
    float* __restrict__ out_slice)
{
    __shared__ float tl[32][64];
    __shared__ float ql[32][64], kl[32][64], vl[32][64];
    __shared__ float sl[32][33];
    int bh = blockIdx.x, tid = threadIdx.x;
    const float* tk = tlg + (size_t)bh * 2048;

#pragma unroll
    for (int j = 0; j < 8; j++) {
        int idx = j * 256 + tid;
        tl[idx >> 6][idx & 63] = tk[idx];
    }
    __syncthreads();
#pragma unroll
    for (int j = 0; j < 8; j++) {
        int idx = j * 256 + tid;
        int g = idx >> 6, d = idx & 63;
        float aq = 0.f, ak = 0.f, av = 0.f;
        for (int e = 0; e < 64; e++) {
            float t = tl[g][e];
            aq += t * Wq[e * 64 + d];
            ak += t * Wk[e * 64 + d];
            av += t * Wv[e * 64 + d];
        }
        ql[g][d] = aq; kl[g][d] = ak; vl[g][d] = av;
    }
    __syncthreads();
#pragma unroll
    for (int j = 0; j < 4; j++) {
        int idx = j * 256 + tid;
        int gq = idx >> 5, gk = idx & 31;
        float s = 0.f;
        for (int d = 0; d < 64; d++) s += ql[gq][d] * kl[gk][d];
        sl[gq][gk] = s * 0.125f;   // 1/sqrt(64)
    }
    __syncthreads();
    if (tid < 32) {
        float m = -1e30f;
        for (int k2 = 0; k2 < 32; k2++) m = fmaxf(m, sl[tid][k2]);
        float s = 0.f;
        for (int k2 = 0; k2 < 32; k2++) { float e = __expf(sl[tid][k2] - m); sl[tid][k2] = e; s += e; }
        float r = 1.0f / s;
        for (int k2 = 0; k2 < 32; k2++) sl[tid][k2] *= r;
    }
    __syncthreads();
#pragma unroll
    for (int j = 0; j < 8; j++) {
        int idx = j * 256 + tid;
        int g = idx >> 6, d = idx & 63;
        float a = 0.f;
        for (int k2 = 0; k2 < 32; k2++) a += sl[g][k2] * vl[k2][d];
        out_slice[(size_t)bh * 2048 + idx] = a;
    }
}

// ---------------- kZ: ZTf[b][ch][tile][lane][8] = frag-order (os@Wout)^T --
__global__ __launch_bounds__(256) void kZ(
    const float* __restrict__ os, const float* __restrict__ Wout,
    u16* __restrict__ ZTf)
{
    int b = blockIdx.x, cb = blockIdx.y;   // grid (4, 16)
    int t = threadIdx.x;
    int c = cb * 16 + (t & 15), kq = t >> 4;
    int tile = c >> 4, lm = c & 15;
    for (int k = kq * 16; k < kq * 16 + 16; k++) {
        int h = k >> 5, g = k & 31;
        const float* osr = os + ((size_t)(b * 8 + h)) * 2048 + g * 64;
        float acc = 0.f;
        for (int d = 0; d < 64; d++)
            acc += osr[d] * Wout[(h * 64 + d) * 256 + c];
        int ch = k >> 5, quad = (k >> 3) & 3, jj = k & 7;
        int lane = quad * 16 + lm;
        ZTf[((size_t)((b * 8 + ch) * 16 + tile)) * 512 + lane * 8 + jj] = f2b(acc);
    }
}

// ---------------- launcher ----------------
extern "C" void kernel_launch(void* const* d_in, const int* in_sizes, int n_in,
                              void* d_out, int out_size, void* d_ws, size_t ws_size,
                              hipStream_t stream)
{
    const float* x      = (const float*)d_in[0];
    const float* Wfx    = (const float*)d_in[1];
    const float* bfx    = (const float*)d_in[2];
    const float* Wx     = (const float*)d_in[3];
    const float* bx     = (const float*)d_in[4];
    const float* Wslice = (const float*)d_in[5];
    const float* bslice = (const float*)d_in[6];
    const float* temp   = (const float*)d_in[7];
    const float* Wq     = (const float*)d_in[8];
    const float* Wk     = (const float*)d_in[9];
    const float* Wv     = (const float*)d_in[10];
    const float* Wout   = (const float*)d_in[11];
    const float* bout   = (const float*)d_in[12];

    char* ws = (char*)d_ws;
    size_t off = 0;
    auto alloc = [&](size_t bytes) {
        void* p = ws + off;
        off = (off + bytes + 255) & ~(size_t)255;
        return p;
    };
    u16*   fxT   = (u16*)  alloc((size_t)512 * BNc * 2);   // 64 MiB
    u16*   swb   = (u16*)  alloc((size_t)BNc * 256 * 2);   // 32 MiB
    u16*   swT   = (u16*)  alloc((size_t)1024 * Nc * 2);   // 32 MiB
    float* tp    = (float*)alloc((size_t)2048 * 2048 * 4); // 16 MiB (64 ky x 32 bh)
    float* np    = (float*)alloc((size_t)2048 * 32 * 4);   // 256 KiB
    float* tl    = (float*)alloc(65536 * 4);               // 256 KiB
    float* osl   = (float*)alloc(65536 * 4);               // 256 KiB
    u16*   ZTf   = (u16*)  alloc(4 * 65536 * 2);           // 512 KiB, chunk-major frag order
    u16*   Ball  = (u16*)  alloc((size_t)768 * 256 * 2);   // WfxT rows 0-511, WxsT 512-767
    u16*   Bfrg  = (u16*)  alloc((size_t)768 * 256 * 2);   // chunk-major frag-ordered Ball
    float* bxs   = (float*)alloc(256 * 4);

    u16* WfxT = Ball;
    u16* WxsT = Ball + (size_t)512 * 256;

    k0_fold<<<257, 256, 0, stream>>>(Wx, Wslice, bx, bslice, WxsT, bxs);
    kprep_wfx<<<512, 256, 0, stream>>>(Wfx, WfxT);
    kfrag<<<96, 256, 0, stream>>>(Ball, Bfrg);

    // fused: fxT = (x @ Wfx + bfx)^T  AND  softmax((x @ Wxs + bxs)/T) -> swb, swT
    kproj<<<dim3(2048, 3), 512, 0, stream>>>(x, Bfrg, bfx, bxs, temp, fxT, swb, swT);

    k4_token_mfma<<<dim3(32, 64), 256, 0, stream>>>(swT, fxT, tp, np);
    k4b_reduce<<<256, 256, 0, stream>>>(tp, np, tl);
    k5_attn<<<32, 256, 0, stream>>>(tl, Wq, Wk, Wv, osl);
    kZ<<<dim3(4, 16), 256, 0, stream>>>(osl, Wout, ZTf);

    // out = swb @ ZTf_b^T + bout -> f32 d_out
    kout<<<2048, 512, 0, stream>>>(swb, ZTf, bout, (float*)d_out);
}

// Round 10
// 333.732 us; speedup vs baseline: 1.5672x; 1.0090x over previous
//
#include <hip/hip_runtime.h>

// Physics_Attention_Irregular_Mesh — round 11
// B=4, N=16384, DIM=256, H=8, D=64, G=32, inner=512. f32 I/O.
// r11 (r10 post-mortem: sched_barrier(0) did NOT pin the B-panel — VGPR
// stayed 48, identical codegen: regalloc remats the const-memory loads at
// use regardless of scheduler fences). Fix: OPAQUE pin via inline asm
// read-write operand  asm volatile("" : "+v"(frag))  on each of the 16
// B-frags, placed just before __syncthreads. The asm defines the value, so
// later uses must consume its output register -> reload is illegal, 64
// VGPRs stay live, all 16 loads issue up-front and pipeline in the VMEM
// queue. Applied to kproj AND kout (same pathology).
//  k4 / k4b / k5 / kZ / preps: unchanged (passed, absmax 3.05e-05).

typedef unsigned short u16;
typedef __attribute__((ext_vector_type(8))) unsigned short ushort8v;
typedef __attribute__((ext_vector_type(4))) unsigned short ushort4v;
typedef __attribute__((ext_vector_type(8))) short short8v;
typedef __attribute__((ext_vector_type(4))) float f32x4;

constexpr int Nc = 16384;
constexpr int BNc = 65536;

__device__ inline float b2f(u16 v) {
    union { unsigned int u; float f; } t; t.u = ((unsigned int)v) << 16; return t.f;
}
__device__ inline u16 f2b(float f) {   // round-to-nearest-even
    union { float f; unsigned int u; } t; t.f = f;
    unsigned int u = t.u;
    return (u16)((u + 0x7fffu + ((u >> 16) & 1u)) >> 16);
}

// Opaque register pin: the asm is a def of v, so the compiler cannot
// rematerialize/reload the value after this point — it must stay in VGPRs.
__device__ __forceinline__ void pinv(short8v& v) {
    asm volatile("" : "+v"(v));
}

// ---------------- prep: fold WxsT[h*32+g][k] = (Wx_h @ Wslice)^T, bxs ------
__global__ __launch_bounds__(256) void k0_fold(
    const float* __restrict__ Wx, const float* __restrict__ Wslice,
    const float* __restrict__ bx, const float* __restrict__ bslice,
    u16* __restrict__ WxsT, float* __restrict__ bxs)
{
    int blk = blockIdx.x, tid = threadIdx.x;
    int h = tid >> 5, g = tid & 31;
    if (blk < 256) {
        int k = blk;
        float acc = 0.f;
        for (int d = 0; d < 64; d++)
            acc += Wx[k * 512 + h * 64 + d] * Wslice[d * 32 + g];
        WxsT[tid * 256 + k] = f2b(acc);
    } else {
        float acc = 0.f;
        for (int d = 0; d < 64; d++)
            acc += bx[h * 64 + d] * Wslice[d * 32 + g];
        bxs[tid] = acc + bslice[g];
    }
}

// ---------------- prep: WfxT[n][k] bf16 ----------------
__global__ __launch_bounds__(256) void kprep_wfx(const float* __restrict__ Wfx,
                                                 u16* __restrict__ WfxT)
{
    int n = blockIdx.x, k = threadIdx.x;        // 512 blocks x 256
    WfxT[n * 256 + k] = f2b(Wfx[k * 512 + n]);
}

// ---------------- kfrag: repack Ball -> chunk-major fragment order --------
// Bf[c=0..7][t=0..47][lane=0..63][jj=0..7]: lane (lm,quad) holds
// Ball[t*16+lm][c*32+quad*8+jj]. One chunk c = contiguous 48 KiB.
__global__ __launch_bounds__(256) void kfrag(const u16* __restrict__ Ball,
                                             u16* __restrict__ Bf)
{
    int g = blockIdx.x * 256 + threadIdx.x;   // 96 blocks -> 24576 threads
    int pair = g >> 6, lane = g & 63;
    int t = pair >> 3, c = pair & 7;
    int n = t * 16 + (lane & 15);
    int k = c * 32 + (lane >> 4) * 8;
    ushort8v v = *(const ushort8v*)(Ball + (size_t)n * 256 + k);
    *(ushort8v*)(Bf + (size_t)((c * 48 + t) * 64 + lane) * 8) = v;
}

// ---------------- kproj: fused projection, barrier-free (B in regs) -------
// Grid (2048, 3) x 512. Block = 32 rows x 16 tiles (tile-group tg).
// Wave q owns tiles {tg*16+2q, tg*16+2q+1} x 32 rows (2 row-frags).
// B: 16 frags in VGPRs, loaded once, PINNED via asm "+v" (opaque def).
// A: 32x256 bf16 in LDS, XOR-swizzled rows, staged once -> ONE barrier.
// Inner: 8 chunks x {2 ds_read_b128 (A, broadcast) + 4 MFMA}. No syncs.
__global__ __launch_bounds__(512, 4) void kproj(
    const float* __restrict__ x, const u16* __restrict__ Bf,
    const float* __restrict__ bfx, const float* __restrict__ bxs,
    const float* __restrict__ temp,
    u16* __restrict__ fxT, u16* __restrict__ swb, u16* __restrict__ swT)
{
    __shared__ u16 As[32 * 256];   // 16 KiB bf16, row-XOR-swizzled
    int tid = threadIdx.x;
    int wave = tid >> 6, lane = tid & 63;
    int lm = lane & 15, quad = lane >> 4;
    int tg = blockIdx.y;
    int row0 = blockIdx.x * 32;
    int T0 = tg * 16 + 2 * wave;           // wave's tile pair T0, T0+1

    // ---- issue B-frag loads: 16 x 16B/lane, coalesced, L2-resident ----
    short8v breg0[8], breg1[8];
#pragma unroll
    for (int c = 0; c < 8; c++) {
        breg0[c] = *(const short8v*)(Bf + (size_t)((c * 48 + T0) * 64 + lane) * 8);
        breg1[c] = *(const short8v*)(Bf + (size_t)((c * 48 + T0 + 1) * 64 + lane) * 8);
    }

    // ---- stage A: 32 rows x 256 f32 -> bf16 LDS (swizzled), once ----
    {
        int row = tid >> 4, colg = tid & 15;       // 512 thr: 64B f32 each
        const f32x4* src = (const f32x4*)(x + (size_t)(row0 + row) * 256 + colg * 16);
        f32x4 v0 = src[0], v1 = src[1], v2 = src[2], v3 = src[3];
        ushort8v o0, o1;
#pragma unroll
        for (int j = 0; j < 4; j++) {
            o0[j] = f2b(v0[j]); o0[4 + j] = f2b(v1[j]);
            o1[j] = f2b(v2[j]); o1[4 + j] = f2b(v3[j]);
        }
        int sw = (row & 7) << 4;
        char* base = (char*)As + row * 512;
        *(ushort8v*)(base + ((colg * 32) ^ sw)) = o0;
        *(ushort8v*)(base + ((colg * 32 + 16) ^ sw)) = o1;
    }

    // ---- opaque pin: B-panel must be materialized in VGPRs here ----
#pragma unroll
    for (int c = 0; c < 8; c++) { pinv(breg0[c]); pinv(breg1[c]); }

    __syncthreads();               // the ONLY barrier

    // ---- main: 8 chunks x {2 A ds_reads + 4 MFMA}, B from regs ----
    f32x4 acc00 = {}, acc01 = {}, acc10 = {}, acc11 = {};
    int swl = (lm & 7) << 4;
    const char* Arow0 = (const char*)As + lm * 512;          // rf=0 row
    const char* Arow1 = (const char*)As + (16 + lm) * 512;   // rf=1 row
#pragma unroll
    for (int c = 0; c < 8; c++) {
        int off = (c * 64 + quad * 16) ^ swl;
        short8v af0 = *(const short8v*)(Arow0 + off);
        short8v af1 = *(const short8v*)(Arow1 + off);
        acc00 = __builtin_amdgcn_mfma_f32_16x16x32_bf16(af0, breg0[c], acc00, 0, 0, 0);
        acc10 = __builtin_amdgcn_mfma_f32_16x16x32_bf16(af1, breg0[c], acc10, 0, 0, 0);
        acc01 = __builtin_amdgcn_mfma_f32_16x16x32_bf16(af0, breg1[c], acc01, 0, 0, 0);
        acc11 = __builtin_amdgcn_mfma_f32_16x16x32_bf16(af1, breg1[c], acc11, 0, 0, 0);
    }

    // ---- epilogue ----
    if (tg < 2) {
        // pure fx tiles
        int nbase = row0 + quad * 4;
#pragma unroll
        for (int i = 0; i < 2; i++) {
            int cc = (T0 + i) * 16 + lm;
            float bv = bfx[cc];
            const f32x4& a0 = i ? acc01 : acc00;
            const f32x4& a1 = i ? acc11 : acc10;
            ushort4v o0, o1;
#pragma unroll
            for (int r = 0; r < 4; r++) { o0[r] = f2b(a0[r] + bv); o1[r] = f2b(a1[r] + bv); }
            *(ushort4v*)(fxT + (size_t)cc * 65536 + nbase) = o0;
            *(ushort4v*)(fxT + (size_t)cc * 65536 + nbase + 16) = o1;
        }
    } else {
        // softmax tiles: wave q = head q; acc*0 -> g=lm, acc*1 -> g=16+lm
        int h = wave;
        int b = row0 >> 14;
        float it = 1.0f / temp[h];
        float bv0 = bxs[h * 32 + lm];
        float bv1 = bxs[h * 32 + 16 + lm];
        size_t gbase = (size_t)((b * 8 + h) * 32);
#pragma unroll
        for (int rf = 0; rf < 2; rf++) {
            const f32x4& A0 = rf ? acc10 : acc00;
            const f32x4& A1 = rf ? acc11 : acc01;
            int nlbase = (row0 & 16383) + rf * 16 + quad * 4;
            ushort4v p0, p1;
#pragma unroll
            for (int r = 0; r < 4; r++) {
                float v0 = (A0[r] + bv0) * it;       // g = lm
                float v1 = (A1[r] + bv1) * it;       // g = 16+lm
                float m = fmaxf(v0, v1);
                m = fmaxf(m, __shfl_xor(m, 1));
                m = fmaxf(m, __shfl_xor(m, 2));
                m = fmaxf(m, __shfl_xor(m, 4));
                m = fmaxf(m, __shfl_xor(m, 8));
                float e0 = __expf(v0 - m), e1 = __expf(v1 - m);
                float s = e0 + e1;
                s += __shfl_xor(s, 1);
                s += __shfl_xor(s, 2);
                s += __shfl_xor(s, 4);
                s += __shfl_xor(s, 8);
                float rs = 1.0f / s;
                float w0 = e0 * rs, w1 = e1 * rs;
                int row = row0 + rf * 16 + quad * 4 + r;
                swb[(size_t)row * 256 + h * 32 + lm] = f2b(w0);
                swb[(size_t)row * 256 + h * 32 + 16 + lm] = f2b(w1);
                p0[r] = f2b(w0); p1[r] = f2b(w1);
            }
            *(ushort4v*)(swT + (gbase + lm) * 16384 + nlbase) = p0;
            *(ushort4v*)(swT + (gbase + 16 + lm) * 16384 + nlbase) = p1;
        }
    }
}

// ---------------- kout: out = swb @ ZTf_b^T + bout, barrier-free ----------
// Same structure as kproj: grid 2048 x 512 thr. Block = 32 rows x 16 tiles;
// wave q owns tiles {2q, 2q+1}. B = ZTf frags pinned in regs (asm "+v");
// A = swb staged once to swizzled LDS (bf16, no conversion). ONE barrier.
__global__ __launch_bounds__(512, 4) void kout(
    const u16* __restrict__ swb, const u16* __restrict__ ZTf,
    const float* __restrict__ bout, float* __restrict__ out)
{
    __shared__ u16 As[32 * 256];   // 16 KiB
    int tid = threadIdx.x;
    int wave = tid >> 6, lane = tid & 63;
    int lm = lane & 15, quad = lane >> 4;
    int row0 = blockIdx.x * 32;
    int T0 = 2 * wave;
    int b = row0 >> 14;

    // ---- B-frag loads ----
    const u16* Zb = ZTf + (size_t)b * 65536;
    short8v breg0[8], breg1[8];
#pragma unroll
    for (int c = 0; c < 8; c++) {
        breg0[c] = *(const short8v*)(Zb + (size_t)((c * 16 + T0) * 64 + lane) * 8);
        breg1[c] = *(const short8v*)(Zb + (size_t)((c * 16 + T0 + 1) * 64 + lane) * 8);
    }

    // ---- stage A: swb 32 rows x 256 bf16 -> swizzled LDS ----
    {
        int row = tid >> 4, colg = tid & 15;   // 32B per thread
        const ushort8v* src = (const ushort8v*)(swb + (size_t)(row0 + row) * 256 + colg * 16);
        ushort8v v0 = src[0], v1 = src[1];
        int sw = (row & 7) << 4;
        char* base = (char*)As + row * 512;
        *(ushort8v*)(base + ((colg * 32) ^ sw)) = v0;
        *(ushort8v*)(base + ((colg * 32 + 16) ^ sw)) = v1;
    }

    // ---- opaque pin ----
#pragma unroll
    for (int c = 0; c < 8; c++) { pinv(breg0[c]); pinv(breg1[c]); }

    __syncthreads();               // the ONLY barrier

    // ---- main loop ----
    f32x4 acc00 = {}, acc01 = {}, acc10 = {}, acc11 = {};
    int swl = (lm & 7) << 4;
    const char* Arow0 = (const char*)As + lm * 512;
    const char* Arow1 = (const char*)As + (16 + lm) * 512;
#pragma unroll
    for (int c = 0; c < 8; c++) {
        int off = (c * 64 + quad * 16) ^ swl;
        short8v af0 = *(const short8v*)(Arow0 + off);
        short8v af1 = *(const short8v*)(Arow1 + off);
        acc00 = __builtin_amdgcn_mfma_f32_16x16x32_bf16(af0, breg0[c], acc00, 0, 0, 0);
        acc10 = __builtin_amdgcn_mfma_f32_16x16x32_bf16(af1, breg0[c], acc10, 0, 0, 0);
        acc01 = __builtin_amdgcn_mfma_f32_16x16x32_bf16(af0, breg1[c], acc01, 0, 0, 0);
        acc11 = __builtin_amdgcn_mfma_f32_16x16x32_bf16(af1, breg1[c], acc11, 0, 0, 0);
    }

    // ---- epilogue: f32 + bias ----
    int cc0 = T0 * 16 + lm, cc1 = cc0 + 16;
    float bv0 = bout[cc0], bv1 = bout[cc1];
#pragma unroll
    for (int r = 0; r < 4; r++) {
        int rowa = row0 + quad * 4 + r;
        int rowb = rowa + 16;
        out[(size_t)rowa * 256 + cc0] = acc00[r] + bv0;
        out[(size_t)rowa * 256 + cc1] = acc01[r] + bv1;
        out[(size_t)rowb * 256 + cc0] = acc10[r] + bv0;
        out[(size_t)rowb * 256 + cc1] = acc11[r] + bv1;
    }
}

// ---------------- k4: token pooling, LDS-staged (swizzled), split-K -------
// Grid (32 bh, 64 ky). Per block: A = swT[bh*32..+32][ky*256..+256] (16KiB),
// B = fxT[h*64..+64][b*16384+ky*256..+256] (32KiB), staged ONCE via
// global_load_lds with XOR-swizzled source (LDS[row][b] = glob[row][b^sw(row)],
// sw(row) = (row&7)<<4 bytes); reads apply the same XOR -> conflict-free.
__global__ __launch_bounds__(256, 4) void k4_token_mfma(
    const u16* __restrict__ swT, const u16* __restrict__ fxT,
    float* __restrict__ token_part, float* __restrict__ norm_part)
{
    __shared__ u16 As[32 * 256];     // 16 KiB
    __shared__ u16 Bs_[64 * 256];    // 32 KiB
    int bh = blockIdx.x, ky = blockIdx.y;
    int b = bh >> 3, h = bh & 7;
    int tid = threadIdx.x, wave = tid >> 6, lane = tid & 63;
    int lm = lane & 15, quad = lane >> 4;
    int mt = wave & 1, dp = wave >> 1;
    int lh = lane >> 5, lb = lane & 31;

#pragma unroll
    for (int i = 0; i < 4; i++) {
        int s = wave * 4 + i;                  // 0..15 -> rows 2s, 2s+1
        int r = 2 * s + lh;
        int sw = ((lb * 16) ^ ((r & 7) << 4)) >> 1;   // u16 offset in row
        const u16* src = swT + (size_t)(bh * 32 + r) * 16384 + ky * 256 + sw;
        __builtin_amdgcn_global_load_lds((const uint32_t*)src,
                                         (uint32_t*)(&As[s * 512]), 16, 0, 0);
    }
#pragma unroll
    for (int i = 0; i < 8; i++) {
        int s = wave * 8 + i;                  // 0..31 -> rows 2s, 2s+1
        int r = 2 * s + lh;
        int sw = ((lb * 16) ^ ((r & 7) << 4)) >> 1;
        const u16* src = fxT + (size_t)(h * 64 + r) * 65536 + (size_t)b * 16384
                         + ky * 256 + sw;
        __builtin_amdgcn_global_load_lds((const uint32_t*)src,
                                         (uint32_t*)(&Bs_[s * 512]), 16, 0, 0);
    }
    __syncthreads();

    int rA = mt * 16 + lm;
    int rB0 = dp * 32 + lm, rB1 = rB0 + 16;
    const char* Ab  = (const char*)As  + rA  * 512;
    const char* Bb0 = (const char*)Bs_ + rB0 * 512;
    const char* Bb1 = (const char*)Bs_ + rB1 * 512;
    int swA  = (rA  & 7) << 4;
    int swB0 = (rB0 & 7) << 4;
    int swB1 = (rB1 & 7) << 4;

    f32x4 acc0 = {}, acc1 = {};
    float nacc = 0.f;
#pragma unroll
    for (int kk = 0; kk < 8; kk++) {
        int base = kk * 64 + quad * 16;
        short8v af = *(const short8v*)(Ab  + (base ^ swA));
        short8v b0 = *(const short8v*)(Bb0 + (base ^ swB0));
        short8v b1 = *(const short8v*)(Bb1 + (base ^ swB1));
        acc0 = __builtin_amdgcn_mfma_f32_16x16x32_bf16(af, b0, acc0, 0, 0, 0);
        acc1 = __builtin_amdgcn_mfma_f32_16x16x32_bf16(af, b1, acc1, 0, 0, 0);
        if (dp == 0) {
            ushort8v au = (ushort8v&)af;
#pragma unroll
            for (int j = 0; j < 8; j++) nacc += b2f(au[j]);
        }
    }
    float* tp = token_part + ((size_t)(ky * 32 + bh)) * 2048;
#pragma unroll
    for (int r = 0; r < 4; r++) {
        int g = mt * 16 + quad * 4 + r;
        tp[g * 64 + dp * 32 + lm] = acc0[r];
        tp[g * 64 + dp * 32 + 16 + lm] = acc1[r];
    }
    if (dp == 0) {
        nacc += __shfl_xor(nacc, 16);
        nacc += __shfl_xor(nacc, 32);
        if (lane < 16)
            norm_part[(ky * 32 + bh) * 32 + mt * 16 + lm] = nacc;
    }
}

// ---------------- k4b: reduce partials -> tl = token/(norm+1e-5) ----------
__global__ __launch_bounds__(256) void k4b_reduce(
    const float* __restrict__ tp, const float* __restrict__ np,
    float* __restrict__ tl)
{
    int t = blockIdx.x * 256 + threadIdx.x;   // 65536
    int bh = t >> 11, e = t & 2047, g = e >> 6;
    float ts = 0.f, ns = 0.f;
    for (int ch = 0; ch < 64; ch++) {
        ts += tp[((size_t)(ch * 32 + bh)) * 2048 + e];
        ns += np[(ch * 32 + bh) * 32 + g];
    }
    tl[t] = ts / (ns + 1e-5f);
}

// ---------------- k5: tiny attention over G tokens ----------------
__global__ __launch_bounds__(256) void k5_attn(
    const float* __restrict__ tlg,
    const float* __restrict__ Wq, const float* __restrict__ Wk, const float* __restrict__ Wv,
    float* __restrict__ out_slice)
{
    __shared__ float tl[32][64];
    __shared__ float ql[32][64], kl[32][64], vl[32][64];
    __shared__ float sl[32][33];
    int bh = blockIdx.x, tid = threadIdx.x;
    const float* tk = tlg + (size_t)bh * 2048;

#pragma unroll
    for (int j = 0; j < 8; j++) {
        int idx = j * 256 + tid;
        tl[idx >> 6][idx & 63] = tk[idx];
    }
    __syncthreads();
#pragma unroll
    for (int j = 0; j < 8; j++) {
        int idx = j * 256 + tid;
        int g = idx >> 6, d = idx & 63;
        float aq = 0.f, ak = 0.f, av = 0.f;
        for (int e = 0; e < 64; e++) {
            float t = tl[g][e];
            aq += t * Wq[e * 64 + d];
            ak += t * Wk[e * 64 + d];
            av += t * Wv[e * 64 + d];
        }
        ql[g][d] = aq; kl[g][d] = ak; vl[g][d] = av;
    }
    __syncthreads();
#pragma unroll
    for (int j = 0; j < 4; j++) {
        int idx = j * 256 + tid;
        int gq = idx >> 5, gk = idx & 31;
        float s = 0.f;
        for (int d = 0; d < 64; d++) s += ql[gq][d] * kl[gk][d];
        sl[gq][gk] = s * 0.125f;   // 1/sqrt(64)
    }
    __syncthreads();
    if (tid < 32) {
        float m = -1e30f;
        for (int k2 = 0; k2 < 32; k2++) m = fmaxf(m, sl[tid][k2]);
        float s = 0.f;
        for (int k2 = 0; k2 < 32; k2++) { float e = __expf(sl[tid][k2] - m); sl[tid][k2] = e; s += e; }
        float r = 1.0f / s;
        for (int k2 = 0; k2 < 32; k2++) sl[tid][k2] *= r;
    }
    __syncthreads();
#pragma unroll
    for (int j = 0; j < 8; j++) {
        int idx = j * 256 + tid;
        int g = idx >> 6, d = idx & 63;
        float a = 0.f;
        for (int k2 = 0; k2 < 32; k2++) a += sl[g][k2] * vl[k2][d];
        out_slice[(size_t)bh * 2048 + idx] = a;
    }
}

// ---------------- kZ: ZTf[b][ch][tile][lane][8] = frag-order (os@Wout)^T --
__global__ __launch_bounds__(256) void kZ(
    const float* __restrict__ os, const float* __restrict__ Wout,
    u16* __restrict__ ZTf)
{
    int b = blockIdx.x, cb = blockIdx.y;   // grid (4, 16)
    int t = threadIdx.x;
    int c = cb * 16 + (t & 15), kq = t >> 4;
    int tile = c >> 4, lm = c & 15;
    for (int k = kq * 16; k < kq * 16 + 16; k++) {
        int h = k >> 5, g = k & 31;
        const float* osr = os + ((size_t)(b * 8 + h)) * 2048 + g * 64;
        float acc = 0.f;
        for (int d = 0; d < 64; d++)
            acc += osr[d] * Wout[(h * 64 + d) * 256 + c];
        int ch = k >> 5, quad = (k >> 3) & 3, jj = k & 7;
        int lane = quad * 16 + lm;
        ZTf[((size_t)((b * 8 + ch) * 16 + tile)) * 512 + lane * 8 + jj] = f2b(acc);
    }
}

// ---------------- launcher ----------------
extern "C" void kernel_launch(void* const* d_in, const int* in_sizes, int n_in,
                              void* d_out, int out_size, void* d_ws, size_t ws_size,
                              hipStream_t stream)
{
    const float* x      = (const float*)d_in[0];
    const float* Wfx    = (const float*)d_in[1];
    const float* bfx    = (const float*)d_in[2];
    const float* Wx     = (const float*)d_in[3];
    const float* bx     = (const float*)d_in[4];
    const float* Wslice = (const float*)d_in[5];
    const float* bslice = (const float*)d_in[6];
    const float* temp   = (const float*)d_in[7];
    const float* Wq     = (const float*)d_in[8];
    const float* Wk     = (const float*)d_in[9];
    const float* Wv     = (const float*)d_in[10];
    const float* Wout   = (const float*)d_in[11];
    const float* bout   = (const float*)d_in[12];

    char* ws = (char*)d_ws;
    size_t off = 0;
    auto alloc = [&](size_t bytes) {
        void* p = ws + off;
        off = (off + bytes + 255) & ~(size_t)255;
        return p;
    };
    u16*   fxT   = (u16*)  alloc((size_t)512 * BNc * 2);   // 64 MiB
    u16*   swb   = (u16*)  alloc((size_t)BNc * 256 * 2);   // 32 MiB
    u16*   swT   = (u16*)  alloc((size_t)1024 * Nc * 2);   // 32 MiB
    float* tp    = (float*)alloc((size_t)2048 * 2048 * 4); // 16 MiB (64 ky x 32 bh)
    float* np    = (float*)alloc((size_t)2048 * 32 * 4);   // 256 KiB
    float* tl    = (float*)alloc(65536 * 4);               // 256 KiB
    float* osl   = (float*)alloc(65536 * 4);               // 256 KiB
    u16*   ZTf   = (u16*)  alloc(4 * 65536 * 2);           // 512 KiB, chunk-major frag order
    u16*   Ball  = (u16*)  alloc((size_t)768 * 256 * 2);   // WfxT rows 0-511, WxsT 512-767
    u16*   Bfrg  = (u16*)  alloc((size_t)768 * 256 * 2);   // chunk-major frag-ordered Ball
    float* bxs   = (float*)alloc(256 * 4);

    u16* WfxT = Ball;
    u16* WxsT = Ball + (size_t)512 * 256;

    k0_fold<<<257, 256, 0, stream>>>(Wx, Wslice, bx, bslice, WxsT, bxs);
    kprep_wfx<<<512, 256, 0, stream>>>(Wfx, WfxT);
    kfrag<<<96, 256, 0, stream>>>(Ball, Bfrg);

    // fused: fxT = (x @ Wfx + bfx)^T  AND  softmax((x @ Wxs + bxs)/T) -> swb, swT
    kproj<<<dim3(2048, 3), 512, 0, stream>>>(x, Bfrg, bfx, bxs, temp, fxT, swb, swT);

    k4_token_mfma<<<dim3(32, 64), 256, 0, stream>>>(swT, fxT, tp, np);
    k4b_reduce<<<256, 256, 0, stream>>>(tp, np, tl);
    k5_attn<<<32, 256, 0, stream>>>(tl, Wq, Wk, Wv, osl);
    kZ<<<dim3(4, 16), 256, 0, stream>>>(osl, Wout, ZTf);

    // out = swb @ ZTf_b^T + bout -> f32 d_out
    kout<<<2048, 512, 0, stream>>>(swb, ZTf, bout, (float*)d_out);
}